// Round 23
// baseline (442.000 us; speedup 1.0000x reference)
//
#include <hip/hip_runtime.h>
#include <hip/hip_bf16.h>

typedef float f32x4 __attribute__((ext_vector_type(4)));
typedef float f32x2 __attribute__((ext_vector_type(2)));
typedef unsigned int u32x4 __attribute__((ext_vector_type(4)));
typedef unsigned int u32x2 __attribute__((ext_vector_type(2)));
typedef _Float16 f16x4 __attribute__((ext_vector_type(4)));
typedef _Float16 f16x2 __attribute__((ext_vector_type(2)));
typedef unsigned short u16;

#define S_LEN 2048
#define HID 2048
#define NHEAD 32
#define NKVH 8
#define HDIM 64

__device__ __forceinline__ unsigned short f2bf_bits(float f) {
    unsigned int u = __builtin_bit_cast(unsigned int, f);
    unsigned int r = u + 0x7fffu + ((u >> 16) & 1u);
    return (unsigned short)(r >> 16);
}
__device__ __forceinline__ float bf2f(unsigned short b) {
    unsigned int u = ((unsigned int)b) << 16;
    return __builtin_bit_cast(float, u);
}
__device__ __forceinline__ unsigned cvt_pk_bf16(float lo, float hi) {
    unsigned d;
    asm("v_cvt_pk_bf16_f32 %0, %1, %2" : "=v"(d) : "v"(lo), "v"(hi));
    return d;
}

__device__ __forceinline__ f32x4 mfma_bf16(u32x4 a, u32x4 b, f32x4 c) {
    asm("v_mfma_f32_16x16x32_bf16 %0, %1, %2, %0" : "+v"(c) : "v"(a), "v"(b));
    return c;
}

__device__ __forceinline__ void gload_lds16(const void* g, void* l) {
    __builtin_amdgcn_global_load_lds(
        (const __attribute__((address_space(1))) void*)g,
        (__attribute__((address_space(3))) void*)l, 16, 0, 0);
}

// ---------------- RMSNorm: f32 [2048][2048] -> bf16 ----------------
__global__ __launch_bounds__(256)
void rmsnorm_k(const float* __restrict__ x, const float* __restrict__ wgt,
               unsigned short* __restrict__ out)
{
    int row = blockIdx.x;
    int t = threadIdx.x;
    const float* xr = x + (size_t)row * HID;
    f32x4 a = *(const f32x4*)(xr + t * 8);
    f32x4 b = *(const f32x4*)(xr + t * 8 + 4);
    float s = 0.f;
#pragma unroll
    for (int i = 0; i < 4; ++i) s += a[i] * a[i] + b[i] * b[i];
#pragma unroll
    for (int off = 32; off > 0; off >>= 1) s += __shfl_down(s, off);
    __shared__ float red[4];
    if ((t & 63) == 0) red[t >> 6] = s;
    __syncthreads();
    float tot = red[0] + red[1] + red[2] + red[3];
    float inv = rsqrtf(tot * (1.0f / (float)HID) + 1e-6f);
    f32x4 wa = *(const f32x4*)(wgt + t * 8);
    f32x4 wb = *(const f32x4*)(wgt + t * 8 + 4);
    unsigned int pk[4];
#pragma unroll
    for (int i = 0; i < 2; ++i) {
        pk[i]     = (unsigned)f2bf_bits(a[2*i] * inv * wa[2*i]) |
                    ((unsigned)f2bf_bits(a[2*i+1] * inv * wa[2*i+1]) << 16);
        pk[i + 2] = (unsigned)f2bf_bits(b[2*i] * inv * wb[2*i]) |
                    ((unsigned)f2bf_bits(b[2*i+1] * inv * wb[2*i+1]) << 16);
    }
    u32x4 ov; ov[0] = pk[0]; ov[1] = pk[1]; ov[2] = pk[2]; ov[3] = pk[3];
    *(u32x4*)(out + (size_t)row * HID + t * 8) = ov;
}

// ---- fused: x1 = x + p0..p3 (f16 partials); out x1 (f32) + rmsnorm(x1) (bf16) ----
__global__ __launch_bounds__(256)
void res_rms(const float* __restrict__ x, const _Float16* __restrict__ p,
             const float* __restrict__ wgt, float* __restrict__ x1out,
             unsigned short* __restrict__ xnout, int n)
{
    int row = blockIdx.x;
    int t = threadIdx.x;
    int base = row * HID + t * 8;
    f32x4 a = *(const f32x4*)(x + base);
    f32x4 b = *(const f32x4*)(x + base + 4);
#pragma unroll
    for (int z = 0; z < 4; ++z) {
        f16x4 h0 = *(const f16x4*)(p + (size_t)z * n + base);
        f16x4 h1 = *(const f16x4*)(p + (size_t)z * n + base + 4);
#pragma unroll
        for (int j = 0; j < 4; ++j) { a[j] += (float)h0[j]; b[j] += (float)h1[j]; }
    }
    *(f32x4*)(x1out + base) = a;
    *(f32x4*)(x1out + base + 4) = b;
    float s = 0.f;
#pragma unroll
    for (int i = 0; i < 4; ++i) s += a[i] * a[i] + b[i] * b[i];
#pragma unroll
    for (int off = 32; off > 0; off >>= 1) s += __shfl_down(s, off);
    __shared__ float red[4];
    if ((t & 63) == 0) red[t >> 6] = s;
    __syncthreads();
    float tot = red[0] + red[1] + red[2] + red[3];
    float inv = rsqrtf(tot * (1.0f / (float)HID) + 1e-6f);
    f32x4 wa = *(const f32x4*)(wgt + t * 8);
    f32x4 wb = *(const f32x4*)(wgt + t * 8 + 4);
    unsigned int pk[4];
#pragma unroll
    for (int i = 0; i < 2; ++i) {
        pk[i]     = (unsigned)f2bf_bits(a[2*i] * inv * wa[2*i]) |
                    ((unsigned)f2bf_bits(a[2*i+1] * inv * wa[2*i+1]) << 16);
        pk[i + 2] = (unsigned)f2bf_bits(b[2*i] * inv * wb[2*i]) |
                    ((unsigned)f2bf_bits(b[2*i+1] * inv * wb[2*i+1]) << 16);
    }
    u32x4 ov; ov[0] = pk[0]; ov[1] = pk[1]; ov[2] = pk[2]; ov[3] = pk[3];
    *(u32x4*)(xnout + base) = ov;
}

// ------------- transpose + convert: f32 [K][N] -> bf16 [N][K] -------------
__global__ __launch_bounds__(256)
void transpose_cvt(const float* __restrict__ in, unsigned short* __restrict__ out,
                   int K, int N)
{
    __shared__ unsigned short tile[64 * 65];
    int kb = blockIdx.y * 64, nb = blockIdx.x * 64;
    int t = threadIdx.x;
    int r = t >> 2, c0 = (t & 3) * 16;
    const float* src = in + (size_t)(kb + r) * N + nb + c0;
#pragma unroll
    for (int j = 0; j < 4; ++j) {
        f32x4 v = *(const f32x4*)(src + j * 4);
#pragma unroll
        for (int i = 0; i < 4; ++i)
            tile[r * 65 + c0 + j * 4 + i] = f2bf_bits(v[i]);
    }
    __syncthreads();
    unsigned short e[16];
#pragma unroll
    for (int j = 0; j < 16; ++j) e[j] = tile[(c0 + j) * 65 + r];
    u32x4 o0, o1;
#pragma unroll
    for (int j = 0; j < 4; ++j) {
        o0[j] = (unsigned)e[2*j] | ((unsigned)e[2*j+1] << 16);
        o1[j] = (unsigned)e[8 + 2*j] | ((unsigned)e[8 + 2*j+1] << 16);
    }
    unsigned short* dst = out + (size_t)(nb + r) * K + kb + c0;
    *(u32x4*)(dst) = o0;
    *(u32x4*)(dst + 8) = o1;
}

// ---- fused split-K reduce + rope + bf16 convert (vectorized): partials -> qkv ----
__global__ __launch_bounds__(256)
void reduce_rope(const _Float16* __restrict__ p, const float* __restrict__ sin_t,
                 const float* __restrict__ cos_t, unsigned short* __restrict__ qkv,
                 int n)
{
    int s = blockIdx.x;
    size_t base = (size_t)s * 3072;
    for (int it = threadIdx.x; it < (NHEAD + NKVH) * 16; it += 256) {
        int slot = it >> 4, dp = (it & 15) * 2;
        int col = slot * 64 + dp;
        f16x2 a0 = *(const f16x2*)(p + base + col);
        f16x2 b0 = *(const f16x2*)(p + (size_t)n + base + col);
        f16x2 a1 = *(const f16x2*)(p + base + col + 32);
        f16x2 b1 = *(const f16x2*)(p + (size_t)n + base + col + 32);
        f32x2 cc = *(const f32x2*)(cos_t + s * 32 + dp);
        f32x2 ss = *(const f32x2*)(sin_t + s * 32 + dp);
        float x0a = (float)a0[0] + (float)b0[0];
        float x0b = (float)a0[1] + (float)b0[1];
        float x1a = (float)a1[0] + (float)b1[0];
        float x1b = (float)a1[1] + (float)b1[1];
        unsigned lo = (unsigned)f2bf_bits(x0a * cc[0] - x1a * ss[0]) |
                      ((unsigned)f2bf_bits(x0b * cc[1] - x1b * ss[1]) << 16);
        unsigned hi = (unsigned)f2bf_bits(x0a * ss[0] + x1a * cc[0]) |
                      ((unsigned)f2bf_bits(x0b * ss[1] + x1b * cc[1]) << 16);
        *(unsigned*)(qkv + base + col)      = lo;
        *(unsigned*)(qkv + base + col + 32) = hi;
    }
    for (int it = threadIdx.x; it < (NKVH * HDIM) / 8; it += 256) {
        int col = 2560 + it * 8;
        f16x4 a0 = *(const f16x4*)(p + base + col);
        f16x4 a1 = *(const f16x4*)(p + base + col + 4);
        f16x4 b0 = *(const f16x4*)(p + (size_t)n + base + col);
        f16x4 b1 = *(const f16x4*)(p + (size_t)n + base + col + 4);
        u32x4 ov;
#pragma unroll
        for (int j = 0; j < 2; ++j) {
            ov[j] = (unsigned)f2bf_bits((float)a0[2*j] + (float)b0[2*j]) |
                    ((unsigned)f2bf_bits((float)a0[2*j+1] + (float)b0[2*j+1]) << 16);
            ov[2 + j] = (unsigned)f2bf_bits((float)a1[2*j] + (float)b1[2*j]) |
                        ((unsigned)f2bf_bits((float)a1[2*j+1] + (float)b1[2*j+1]) << 16);
        }
        *(u32x4*)(qkv + base + col) = ov;
    }
}

// ---- V^T prepass: qkv v-slice [S][kvh*64+d] -> vT[kvh][d][S] (slot-swizzled) ----
__global__ __launch_bounds__(256)
void transpose_v(const unsigned short* __restrict__ qkv, unsigned short* __restrict__ vT)
{
    __shared__ unsigned short tile[64][80];
    int kb = blockIdx.x * 64, kvh = blockIdx.y;
    int t = threadIdx.x;
    int r = t >> 2, c0 = (t & 3) * 16;
    const unsigned short* src = qkv + (size_t)(kb + r) * 3072 + 2560 + kvh * 64 + c0;
    u32x4 v0 = *(const u32x4*)(src);
    u32x4 v1 = *(const u32x4*)(src + 8);
    *(u32x4*)&tile[r][c0] = v0;
    *(u32x4*)&tile[r][c0 + 8] = v1;
    __syncthreads();
    int d = t >> 2, k0 = (t & 3) * 16;
    unsigned short e[16];
#pragma unroll
    for (int j = 0; j < 16; ++j) e[j] = tile[k0 + j][d];
    u32x4 o0, o1;
#pragma unroll
    for (int j = 0; j < 4; ++j) {
        o0[j] = (unsigned)e[2*j] | ((unsigned)e[2*j+1] << 16);
        o1[j] = (unsigned)e[8 + 2*j] | ((unsigned)e[8 + 2*j+1] << 16);
    }
    int s0 = ((k0 >> 3) ^ (d & 7)) & 7;
    int s1 = (((k0 >> 3) + 1) ^ (d & 7)) & 7;
    unsigned short* dst = vT + ((size_t)kvh * 64 + d) * 2048 + kb;
    *(u32x4*)(dst + s0 * 8) = o0;
    *(u32x4*)(dst + s1 * 8) = o1;
}

// ---- 256x256 GEMM, merged phases + register-pipelined fragment reads ----
template <int KK>
__device__ __forceinline__ void phaseP(u16* lds, int cur, f32x4 (&acc)[8][4],
                                       u32x4 (&rcur)[12], u32x4 (&rnext)[12],
                                       int aoff, int boff,
                                       const u16* Asrc, const u16* Bsrc,
                                       int lda, int kt_stage,
                                       int dst0, int dst1)
{
    asm volatile("s_waitcnt vmcnt(4)" ::: "memory");
    {   // prefetch fragments for NEXT phase
        int nbuf = (KK == 0) ? cur : (cur ^ 1);
        int nslot = (KK == 0) ? 2 : 0;
        const u16* ah = lds + (nbuf * 4 + nslot) * 8192 + aoff;
        const u16* bh = lds + (nbuf * 4 + nslot + 1) * 8192 + boff;
#pragma unroll
        for (int m = 0; m < 8; ++m)
            rnext[m] = *(const u32x4*)(ah + (m >> 2) * 2048 + (m & 3) * 512);
#pragma unroll
        for (int ni = 0; ni < 4; ++ni)
            rnext[8 + ni] = *(const u32x4*)(bh + ni * 512);
    }
    {   // stage one k-half of a future tile
        const u16* sa = Asrc + (size_t)kt_stage * 64 + (KK == 0 ? 32 : 0);
        const u16* sb = Bsrc + (size_t)kt_stage * 64 + (KK == 0 ? 32 : 0);
        int dbuf = (KK == 0) ? (cur ^ 1) : cur;
        u16* dA = lds + (dbuf * 4 + (KK == 0 ? 2 : 0)) * 8192;
        u16* dB = lds + (dbuf * 4 + (KK == 0 ? 3 : 1)) * 8192;
        gload_lds16(sa, dA + dst0);
        gload_lds16(sa + (size_t)128 * lda, dA + dst1);
        gload_lds16(sb, dB + dst0);
        gload_lds16(sb + (size_t)128 * lda, dB + dst1);
    }
    __builtin_amdgcn_sched_barrier(0);
    __builtin_amdgcn_s_setprio(1);
#pragma unroll
    for (int m = 0; m < 8; ++m)
#pragma unroll
        for (int ni = 0; ni < 4; ++ni)
            acc[m][ni] = mfma_bf16(rcur[m], rcur[8 + ni], acc[m][ni]);
    __builtin_amdgcn_s_setprio(0);
    __builtin_amdgcn_s_barrier();
}

template <int EPI>
__global__ __launch_bounds__(512, 2)
void gemm8p(const u16* __restrict__ A, const u16* __restrict__ Bt,
            void* __restrict__ outp, const void* __restrict__ auxp,
            int M, int N, int Kc, int lda)
{
    extern __shared__ u16 lds[];   // 128 KiB
    const int tid = threadIdx.x;
    const int w = tid >> 6, l = tid & 63;
    const int wm = w >> 2, wn = w & 3;
    const int l4 = l >> 4, l15 = l & 15;
    const int zb = blockIdx.y;

    int wg = blockIdx.x, nwg = gridDim.x;
    int swzb = ((nwg & 7) == 0) ? ((wg & 7) * (nwg >> 3) + (wg >> 3)) : wg;
    int rbs = M >> 8;
    int rb = swzb % rbs, cb = swzb / rbs;

    const int sw = ((tid & 3) ^ ((tid >> 3) & 3)) * 8;
    const int srow = tid >> 2;
    const u16* Asrc = A + (size_t)(rb * 256 + srow) * lda + (size_t)zb * Kc + sw;
    const u16* Bsrc = Bt + (size_t)(cb * 256 + srow) * lda + (size_t)zb * Kc + sw;
    const int dst0 = tid * 8, dst1 = (512 + tid) * 8;

    const int rswz = (l15 >> 1) & 3;
    const int aoff = (wm * 128 + l15) * 32 + (l4 ^ rswz) * 8;
    const int boff = (wn * 64 + l15) * 32 + (l4 ^ rswz) * 8;

    f32x4 acc[8][4] = {};
    u32x4 rA[12], rB[12];
    const int NT = Kc >> 6;

    {
#pragma unroll
        for (int h = 0; h < 2; ++h) {
            const u16* sA = Asrc + h * 32;
            const u16* sB = Bsrc + h * 32;
            gload_lds16(sA, lds + (h * 2) * 8192 + dst0);
            gload_lds16(sA + (size_t)128 * lda, lds + (h * 2) * 8192 + dst1);
            gload_lds16(sB, lds + (h * 2 + 1) * 8192 + dst0);
            gload_lds16(sB + (size_t)128 * lda, lds + (h * 2 + 1) * 8192 + dst1);
        }
        int t1 = (NT > 1) ? 1 : 0;
        const u16* sA = Asrc + (size_t)t1 * 64;
        const u16* sB = Bsrc + (size_t)t1 * 64;
        gload_lds16(sA, lds + (4 + 0) * 8192 + dst0);
        gload_lds16(sA + (size_t)128 * lda, lds + (4 + 0) * 8192 + dst1);
        gload_lds16(sB, lds + (4 + 1) * 8192 + dst0);
        gload_lds16(sB + (size_t)128 * lda, lds + (4 + 1) * 8192 + dst1);
    }
    asm volatile("s_waitcnt vmcnt(8)" ::: "memory");
    __builtin_amdgcn_s_barrier();
    {   // pre-read phase-(0,0) fragments (buf0 slots 0,1)
        const u16* ah = lds + aoff;
        const u16* bh = lds + 8192 + boff;
#pragma unroll
        for (int m = 0; m < 8; ++m)
            rA[m] = *(const u32x4*)(ah + (m >> 2) * 2048 + (m & 3) * 512);
#pragma unroll
        for (int ni = 0; ni < 4; ++ni)
            rA[8 + ni] = *(const u32x4*)(bh + ni * 512);
    }

    for (int t = 0; t < NT; ++t) {
        int cur = t & 1;
        int k1 = (t + 1 < NT) ? t + 1 : 0;
        int k2 = (t + 2 < NT) ? t + 2 : 0;
        phaseP<0>(lds, cur, acc, rA, rB, aoff, boff, Asrc, Bsrc, lda, k1, dst0, dst1);
        phaseP<1>(lds, cur, acc, rB, rA, aoff, boff, Asrc, Bsrc, lda, k2, dst0, dst1);
    }
    asm volatile("s_waitcnt vmcnt(0)" ::: "memory");

    int row0 = rb * 256 + wm * 128 + l4 * 4;
    int col0 = cb * 256 + wn * 64 + l15;
#pragma unroll
    for (int mi = 0; mi < 8; ++mi) {
#pragma unroll
        for (int ni = 0; ni < 4; ++ni) {
#pragma unroll
            for (int r = 0; r < 4; ++r) {
                int row = row0 + mi * 16 + r;
                int col = col0 + ni * 16;
                size_t idx = (size_t)row * N + col;
                float v = acc[mi][ni][r];
                if (EPI == 1) {
                    float sv = v / (1.0f + __expf(-v));
                    ((unsigned short*)outp)[idx] = f2bf_bits(sv);
                } else if (EPI == 2) {
                    float gv = bf2f(((const unsigned short*)auxp)[idx]);
                    ((unsigned short*)outp)[idx] = f2bf_bits(v * gv);
                } else {
                    ((_Float16*)outp)[(size_t)zb * M * N + idx] = (_Float16)v;
                }
            }
        }
    }
}

// -------- fused gate+up, merged phases + register-pipelined reads --------
template <int KK>
__device__ __forceinline__ void phasePgu(u16* lds, int cur, f32x4 (&acc)[8][4],
                                         u32x4 (&rcur)[12], u32x4 (&rnext)[12],
                                         int aoff, int boffg, int boffu,
                                         const u16* Asrc, const u16* Bg, const u16* Bu,
                                         int lda, int kt_stage,
                                         int dst0, int dst1)
{
    asm volatile("s_waitcnt vmcnt(4)" ::: "memory");
    {
        int nbuf = (KK == 0) ? cur : (cur ^ 1);
        int nslot = (KK == 0) ? 2 : 0;
        const u16* ah = lds + (nbuf * 4 + nslot) * 8192 + aoff;
        const u16* bh = lds + (nbuf * 4 + nslot + 1) * 8192;
#pragma unroll
        for (int m = 0; m < 8; ++m)
            rnext[m] = *(const u32x4*)(ah + (m >> 2) * 2048 + (m & 3) * 512);
#pragma unroll
        for (int ni = 0; ni < 2; ++ni) {
            rnext[8 + ni]  = *(const u32x4*)(bh + boffg + ni * 512);
            rnext[10 + ni] = *(const u32x4*)(bh + boffu + ni * 512);
        }
    }
    {
        int koff = (KK == 0 ? 32 : 0);
        const u16* sa = Asrc + (size_t)kt_stage * 64 + koff;
        int dbuf = (KK == 0) ? (cur ^ 1) : cur;
        u16* dA = lds + (dbuf * 4 + (KK == 0 ? 2 : 0)) * 8192;
        u16* dB = lds + (dbuf * 4 + (KK == 0 ? 3 : 1)) * 8192;
        gload_lds16(sa, dA + dst0);
        gload_lds16(sa + (size_t)128 * lda, dA + dst1);
        gload_lds16(Bg + (size_t)kt_stage * 64 + koff, dB + dst0);
        gload_lds16(Bu + (size_t)kt_stage * 64 + koff, dB + dst1);
    }
    __builtin_amdgcn_sched_barrier(0);
    __builtin_amdgcn_s_setprio(1);
#pragma unroll
    for (int m = 0; m < 8; ++m)
#pragma unroll
        for (int ni = 0; ni < 4; ++ni)
            acc[m][ni] = mfma_bf16(rcur[m], rcur[8 + ni], acc[m][ni]);
    __builtin_amdgcn_s_setprio(0);
    __builtin_amdgcn_s_barrier();
}

__global__ __launch_bounds__(512, 2)
void gemm8p_gu(const u16* __restrict__ A, const u16* __restrict__ WgT,
               const u16* __restrict__ WuT, unsigned short* __restrict__ outp,
               int M, int Nfull, int K)
{
    extern __shared__ u16 lds[];   // 128 KiB
    const int tid = threadIdx.x;
    const int w = tid >> 6, l = tid & 63;
    const int wm = w >> 2, wn = w & 3;
    const int l4 = l >> 4, l15 = l & 15;

    int wg = blockIdx.x, nwg = gridDim.x;
    int swzb = ((nwg & 7) == 0) ? ((wg & 7) * (nwg >> 3) + (wg >> 3)) : wg;
    int rbs = M >> 8;
    int rb = swzb % rbs, cb = swzb / rbs;

    const int sw = ((tid & 3) ^ ((tid >> 3) & 3)) * 8;
    const int srow = tid >> 2;
    const u16* Asrc = A + (size_t)(rb * 256 + srow) * K + sw;
    const u16* Bg = WgT + (size_t)(cb * 128 + srow) * K + sw;
    const u16* Bu = WuT + (size_t)(cb * 128 + srow) * K + sw;
    const int dst0 = tid * 8, dst1 = (512 + tid) * 8;

    const int rswz = (l15 >> 1) & 3;
    const int aoff  = (wm * 128 + l15) * 32 + (l4 ^ rswz) * 8;
    const int boffg = (wn * 32 + l15) * 32 + (l4 ^ rswz) * 8;
    const int boffu = (128 + wn * 32 + l15) * 32 + (l4 ^ rswz) * 8;

    f32x4 acc[8][4] = {};
    u32x4 rA[12], rB[12];
    const int NT = K >> 6;

    {
#pragma unroll
        for (int h = 0; h < 2; ++h) {
            const u16* sA = Asrc + h * 32;
            gload_lds16(sA, lds + (h * 2) * 8192 + dst0);
            gload_lds16(sA + (size_t)128 * K, lds + (h * 2) * 8192 + dst1);
            gload_lds16(Bg + h * 32, lds + (h * 2 + 1) * 8192 + dst0);
            gload_lds16(Bu + h * 32, lds + (h * 2 + 1) * 8192 + dst1);
        }
        const u16* sA = Asrc + 64;
        gload_lds16(sA, lds + (4 + 0) * 8192 + dst0);
        gload_lds16(sA + (size_t)128 * K, lds + (4 + 0) * 8192 + dst1);
        gload_lds16(Bg + 64, lds + (4 + 1) * 8192 + dst0);
        gload_lds16(Bu + 64, lds + (4 + 1) * 8192 + dst1);
    }
    asm volatile("s_waitcnt vmcnt(8)" ::: "memory");
    __builtin_amdgcn_s_barrier();
    {
        const u16* ah = lds + aoff;
        const u16* bh = lds + 8192;
#pragma unroll
        for (int m = 0; m < 8; ++m)
            rA[m] = *(const u32x4*)(ah + (m >> 2) * 2048 + (m & 3) * 512);
#pragma unroll
        for (int ni = 0; ni < 2; ++ni) {
            rA[8 + ni]  = *(const u32x4*)(bh + boffg + ni * 512);
            rA[10 + ni] = *(const u32x4*)(bh + boffu + ni * 512);
        }
    }

    for (int t = 0; t < NT; ++t) {
        int cur = t & 1;
        int k1 = (t + 1 < NT) ? t + 1 : 0;
        int k2 = (t + 2 < NT) ? t + 2 : 0;
        phasePgu<0>(lds, cur, acc, rA, rB, aoff, boffg, boffu, Asrc, Bg, Bu, K, k1, dst0, dst1);
        phasePgu<1>(lds, cur, acc, rB, rA, aoff, boffg, boffu, Asrc, Bg, Bu, K, k2, dst0, dst1);
    }
    asm volatile("s_waitcnt vmcnt(0)" ::: "memory");

    int row0 = rb * 256 + wm * 128 + l4 * 4;
    int col0 = cb * 128 + wn * 32 + l15;
#pragma unroll
    for (int mi = 0; mi < 8; ++mi) {
#pragma unroll
        for (int ni = 0; ni < 2; ++ni) {
#pragma unroll
            for (int r = 0; r < 4; ++r) {
                int row = row0 + mi * 16 + r;
                int col = col0 + ni * 16;
                float gv = acc[mi][ni][r];
                float uv = acc[mi][ni + 2][r];
                float sv = gv / (1.0f + __expf(-gv)) * uv;
                outp[(size_t)row * Nfull + col] = f2bf_bits(sv);
            }
        }
    }
}

// ---------------- split-K reduce: out += p0+p1+p2+p3 (f16 partials) ----------------
__global__ __launch_bounds__(256)
void reduce_add4(float* __restrict__ out, const _Float16* __restrict__ p, int n)
{
    int i = (blockIdx.x * 256 + threadIdx.x) * 4;
    f32x4 a = *(const f32x4*)(out + i);
#pragma unroll
    for (int z = 0; z < 4; ++z) {
        f16x4 h = *(const f16x4*)(p + (size_t)z * n + i);
#pragma unroll
        for (int j = 0; j < 4; ++j) a[j] += (float)h[j];
    }
    *(f32x4*)(out + i) = a;
}

// ------- causal GQA flash attention (swapped QK^T, in-reg softmax, T5, unpaired) -------
__global__ __launch_bounds__(256)
void attn_fwd(const unsigned short* __restrict__ qkv,
              const unsigned short* __restrict__ vT,
              unsigned short* __restrict__ out)
{
    int qb = blockIdx.x, h = blockIdx.y, kvh = h >> 2;
    int t = threadIdx.x, w = t >> 6, l = t & 63;
    int l4 = l >> 4, l15 = l & 15;
    __shared__ unsigned short Ks[2][64 * 64];
    __shared__ unsigned short Vs[2][64 * 64];

    const unsigned short* Kg = qkv + HID + kvh * 64;
    const unsigned short* Vg = vT + (size_t)kvh * 64 * 2048;

    int ch0 = w * 2, ch1 = w * 2 + 1;
    int rsub = l >> 3;
    int ksw = ((l & 7) ^ (rsub & 7)) * 8;
    int vcol = (l & 7) * 8;
    int sw0 = (l4 ^ (l15 & 7)) * 8;
    int sw1 = ((l4 | 4) ^ (l15 & 7)) * 8;
    int srcA = ((l >> 4) & 1) * 32 + l15;
    int srcB = srcA + 16;
    bool hi32 = (l & 32) != 0;

#define STAGE_KV(buf, kt)                                                         \
    {                                                                             \
        gload_lds16(Kg + (size_t)((kt) * 64 + ch0 * 8 + rsub) * 3072 + ksw,       \
                    &Ks[buf][ch0 * 512]);                                         \
        gload_lds16(Kg + (size_t)((kt) * 64 + ch1 * 8 + rsub) * 3072 + ksw,       \
                    &Ks[buf][ch1 * 512]);                                         \
        gload_lds16(Vg + (size_t)(ch0 * 8 + rsub) * 2048 + (kt) * 64 + vcol,      \
                    &Vs[buf][ch0 * 512]);                                         \
        gload_lds16(Vg + (size_t)(ch1 * 8 + rsub) * 2048 + (kt) * 64 + vcol,      \
                    &Vs[buf][ch1 * 512]);                                         \
    }

    const float SC2 = 0.18033688f;
    const float THR = 44.36f;
    const float BIG = -3.0e38f;

    int qrow0 = qb * 64 + w * 16;
    STAGE_KV(0, 0);
    const unsigned short* qg = qkv + (size_t)(qrow0 + l15) * 3072 + h * 64 + l4 * 8;
    u32x4 aq0 = *(const u32x4*)(qg);
    u32x4 aq1 = *(const u32x4*)(qg + 32);
    f32x4 o[4] = {};
    float m = BIG, ls = 0.f;
    __syncthreads();
    int cur = 0;
    for (int kt = 0; kt <= qb; ++kt) {
        if (kt < qb) STAGE_KV(cur ^ 1, kt + 1);
        f32x4 sc[4];
        __builtin_amdgcn_s_setprio(1);
#pragma unroll
        for (int n = 0; n < 4; ++n) {
            const unsigned short* kb_ = &Ks[cur][(n * 16 + l15) * 64];
            u32x4 b0 = *(const u32x4*)(kb_ + sw0);
            u32x4 b1 = *(const u32x4*)(kb_ + sw1);
            f32x4 z = {};
            z = mfma_bf16(b0, aq0, z);
            z = mfma_bf16(b1, aq1, z);
            sc[n] = z;
        }
        __builtin_amdgcn_s_setprio(0);
        if (kt == qb) {
            int qloc = w * 16 + l15;
#pragma unroll
            for (int n = 0; n < 4; ++n)
#pragma unroll
                for (int r = 0; r < 4; ++r)
                    if (n * 16 + l4 * 4 + r > qloc) sc[n][r] = BIG;
        }
        float rmax = BIG;
#pragma unroll
        for (int n = 0; n < 4; ++n)
#pragma unroll
            for (int r = 0; r < 4; ++r) rmax = fmaxf(rmax, sc[n][r]);
        rmax = fmaxf(rmax, __shfl_xor(rmax, 16));
        rmax = fmaxf(rmax, __shfl_xor(rmax, 32));
        if (__ballot(rmax - m > THR)) {
            float mn = fmaxf(m, rmax);
            float al = __builtin_exp2f((m - mn) * SC2);
            m = mn;
            ls *= al;
#pragma unroll
            for (int nd = 0; nd < 4; ++nd)
#pragma unroll
                for (int r = 0; r < 4; ++r) o[nd][r] *= al;
        }
        float ms = m * SC2, rs = 0.f;
#pragma unroll
        for (int n = 0; n < 4; ++n)
#pragma unroll
            for (int r = 0; r < 4; ++r) {
                float pe = __builtin_exp2f(__builtin_fmaf(sc[n][r], SC2, -ms));
                sc[n][r] = pe;
                rs += pe;
            }
        rs += __shfl_xor(rs, 16);
        rs += __shfl_xor(rs, 32);
        ls += rs;
        unsigned pk0[2], pk1[2], pk2[2], pk3[2];
#pragma unroll
        for (int rr = 0; rr < 2; ++rr) {
            pk0[rr] = cvt_pk_bf16(sc[0][2*rr], sc[0][2*rr+1]);
            pk1[rr] = cvt_pk_bf16(sc[1][2*rr], sc[1][2*rr+1]);
            pk2[rr] = cvt_pk_bf16(sc[2][2*rr], sc[2][2*rr+1]);
            pk3[rr] = cvt_pk_bf16(sc[3][2*rr], sc[3][2*rr+1]);
        }
        u32x4 W1, W2;
        {
            unsigned a0, a1;
            a0 = __shfl(pk0[0], srcA); a1 = __shfl(pk1[0], srcA); W1[0] = hi32 ? a1 : a0;
            a0 = __shfl(pk0[1], srcA); a1 = __shfl(pk1[1], srcA); W1[1] = hi32 ? a1 : a0;
            a0 = __shfl(pk0[0], srcB); a1 = __shfl(pk1[0], srcB); W1[2] = hi32 ? a1 : a0;
            a0 = __shfl(pk0[1], srcB); a1 = __shfl(pk1[1], srcB); W1[3] = hi32 ? a1 : a0;
            a0 = __shfl(pk2[0], srcA); a1 = __shfl(pk3[0], srcA); W2[0] = hi32 ? a1 : a0;
            a0 = __shfl(pk2[1], srcA); a1 = __shfl(pk3[1], srcA); W2[1] = hi32 ? a1 : a0;
            a0 = __shfl(pk2[0], srcB); a1 = __shfl(pk3[0], srcB); W2[2] = hi32 ? a1 : a0;
            a0 = __shfl(pk2[1], srcB); a1 = __shfl(pk3[1], srcB); W2[3] = hi32 ? a1 : a0;
        }
        __builtin_amdgcn_s_setprio(1);
#pragma unroll
        for (int nd = 0; nd < 4; ++nd) {
            const unsigned short* vb = &Vs[cur][(nd * 16 + l15) * 64];
            u32x4 bv0 = *(const u32x4*)(vb + sw0);
            u32x4 bv1 = *(const u32x4*)(vb + sw1);
            o[nd] = mfma_bf16(bv0, W1, o[nd]);
            o[nd] = mfma_bf16(bv1, W2, o[nd]);
        }
        __builtin_amdgcn_s_setprio(0);
        __syncthreads();
        cur ^= 1;
    }
#undef STAGE_KV
    float linv = 1.0f / ls;
    unsigned short* orow = out + (size_t)(qrow0 + l15) * HID + h * 64 + l4 * 4;
#pragma unroll
    for (int nd = 0; nd < 4; ++nd) {
        u32x2 wv;
        wv[0] = cvt_pk_bf16(o[nd][0] * linv, o[nd][1] * linv);
        wv[1] = cvt_pk_bf16(o[nd][2] * linv, o[nd][3] * linv);
        *(u32x2*)(orow + nd * 16) = wv;
    }
}

extern "C" void kernel_launch(void* const* d_in, const int* in_sizes, int n_in,
                              void* d_out, int out_size, void* d_ws, size_t ws_size,
                              hipStream_t stream)
{
    const float* x     = (const float*)d_in[0];
    const float* sin_t = (const float*)d_in[1];
    const float* cos_t = (const float*)d_in[2];
    const float* ln1w  = (const float*)d_in[3];
    const float* ln2w  = (const float*)d_in[4];
    const float* wq    = (const float*)d_in[5];
    const float* wk    = (const float*)d_in[6];
    const float* wv    = (const float*)d_in[7];
    const float* wo    = (const float*)d_in[8];
    const float* wg    = (const float*)d_in[9];
    const float* wu    = (const float*)d_in[10];
    const float* wd    = (const float*)d_in[11];
    float* out = (float*)d_out;

    char* ws = (char*)d_ws;
    if (ws_size < 113246208u) return;
    unsigned short* wT    = (unsigned short*)(ws);                 // [0, 33.5MB)
    unsigned short* xn    = (unsigned short*)(ws + 33554432u);     // [33.5, 41.9MB)
    unsigned short* qkv   = (unsigned short*)(ws + 41943040u);     // [41.9, 54.5MB) attn window
    unsigned short* attn  = (unsigned short*)(ws + 54525952u);     // [54.5, 62.9MB)
    unsigned short* vT    = (unsigned short*)(ws + 62914560u);     // [62.9, 65.0MB)
    unsigned short* wuT   = (unsigned short*)(ws + 41943040u);     // [41.9, 75.4MB) MLP window
    _Float16*       part  = (_Float16*)(ws + 41943040u);           // [41.9, 75.4MB) down window
    unsigned short* g     = (unsigned short*)(ws + 79691776u);     // [79.7, 113.2MB)
    _Float16*       opart = (_Float16*)(ws + 79691776u);           // o-proj window
    _Float16*       qpart = (_Float16*)(ws + 79691776u);           // qkv-proj window

    hipFuncSetAttribute(reinterpret_cast<const void*>(&gemm8p<5>),
                        hipFuncAttributeMaxDynamicSharedMemorySize, 131072);
    hipFuncSetAttribute(reinterpret_cast<const void*>(&gemm8p_gu),
                        hipFuncAttributeMaxDynamicSharedMemorySize, 131072);

    // x -> rmsnorm -> xn (bf16)
    rmsnorm_k<<<S_LEN, 256, 0, stream>>>(x, ln1w, xn);

    // wq|wk|wv -> wT as [3072][2048] transposed bf16
    transpose_cvt<<<dim3(32, 32), 256, 0, stream>>>(wq, wT, 2048, 2048);
    transpose_cvt<<<dim3(8, 32), 256, 0, stream>>>(wk, wT + (size_t)2048 * 2048, 2048, 512);
    transpose_cvt<<<dim3(8, 32), 256, 0, stream>>>(wv, wT + (size_t)2560 * 2048, 2048, 512);

    // qkv partials = xn @ [wq wk wv]   [split-K=2, f16 partials]
    gemm8p<5><<<dim3(96, 2), 512, 131072, stream>>>(xn, wT, qpart, nullptr, 2048, 3072, 1024, 2048);

    // fused: qkv = reduce(partials) + rope(q,k) + bf16 convert  [vectorized]
    reduce_rope<<<S_LEN, 256, 0, stream>>>(qpart, sin_t, cos_t, qkv, 6291456);

    // v -> vT (swizzled)
    transpose_v<<<dim3(32, 8), 256, 0, stream>>>(qkv, vT);

    // attention (unpaired q-tiles: 1024 blocks, 4-5/CU co-resident)
    attn_fwd<<<dim3(32, 32), 256, 0, stream>>>(qkv, vT, attn);

    // o-proj: split-K=4 (f16 partials)
    transpose_cvt<<<dim3(32, 32), 256, 0, stream>>>(wo, wT, 2048, 2048);
    gemm8p<5><<<dim3(64, 4), 512, 131072, stream>>>(attn, wT, opart, nullptr, 2048, 2048, 512, 2048);

    // fused: d_out = x1 = x + Σp ; xn = rmsnorm(x1, ln2w)
    res_rms<<<S_LEN, 256, 0, stream>>>(x, opart, ln2w, out, xn, 4194304);

    // fused gate+up: g = silu(xn @ w_gate) * (xn @ w_up)
    transpose_cvt<<<dim3(128, 32), 256, 0, stream>>>(wg, wT, 2048, 8192);
    transpose_cvt<<<dim3(128, 32), 256, 0, stream>>>(wu, wuT, 2048, 8192);
    gemm8p_gu<<<dim3(512), 512, 131072, stream>>>(xn, wT, wuT, g, 2048, 8192, 2048);

    // down split-K=4 (f16 partials)
    transpose_cvt<<<dim3(32, 128), 256, 0, stream>>>(wd, wT, 8192, 2048);
    gemm8p<5><<<dim3(64, 4), 512, 131072, stream>>>(g, wT, part, nullptr, 2048, 2048, 2048, 8192);

    // d_out (holds x1) += part0+part1+part2+part3
    reduce_add4<<<4096, 256, 0, stream>>>(out, part, 4194304);
}

// Round 24
// 413.697 us; speedup vs baseline: 1.0684x; 1.0684x over previous
//
#include <hip/hip_runtime.h>
#include <hip/hip_bf16.h>

typedef float f32x4 __attribute__((ext_vector_type(4)));
typedef float f32x2 __attribute__((ext_vector_type(2)));
typedef unsigned int u32x4 __attribute__((ext_vector_type(4)));
typedef unsigned int u32x2 __attribute__((ext_vector_type(2)));
typedef _Float16 f16x4 __attribute__((ext_vector_type(4)));
typedef _Float16 f16x2 __attribute__((ext_vector_type(2)));
typedef unsigned short u16;

#define S_LEN 2048
#define HID 2048
#define NHEAD 32
#define NKVH 8
#define HDIM 64

__device__ __forceinline__ unsigned short f2bf_bits(float f) {
    unsigned int u = __builtin_bit_cast(unsigned int, f);
    unsigned int r = u + 0x7fffu + ((u >> 16) & 1u);
    return (unsigned short)(r >> 16);
}
__device__ __forceinline__ float bf2f(unsigned short b) {
    unsigned int u = ((unsigned int)b) << 16;
    return __builtin_bit_cast(float, u);
}
__device__ __forceinline__ unsigned cvt_pk_bf16(float lo, float hi) {
    unsigned d;
    asm("v_cvt_pk_bf16_f32 %0, %1, %2" : "=v"(d) : "v"(lo), "v"(hi));
    return d;
}

__device__ __forceinline__ f32x4 mfma_bf16(u32x4 a, u32x4 b, f32x4 c) {
    asm("v_mfma_f32_16x16x32_bf16 %0, %1, %2, %0" : "+v"(c) : "v"(a), "v"(b));
    return c;
}

__device__ __forceinline__ void gload_lds16(const void* g, void* l) {
    __builtin_amdgcn_global_load_lds(
        (const __attribute__((address_space(1))) void*)g,
        (__attribute__((address_space(3))) void*)l, 16, 0, 0);
}

// ---------------- RMSNorm: f32 [2048][2048] -> bf16 ----------------
__global__ __launch_bounds__(256)
void rmsnorm_k(const float* __restrict__ x, const float* __restrict__ wgt,
               unsigned short* __restrict__ out)
{
    int row = blockIdx.x;
    int t = threadIdx.x;
    const float* xr = x + (size_t)row * HID;
    f32x4 a = *(const f32x4*)(xr + t * 8);
    f32x4 b = *(const f32x4*)(xr + t * 8 + 4);
    float s = 0.f;
#pragma unroll
    for (int i = 0; i < 4; ++i) s += a[i] * a[i] + b[i] * b[i];
#pragma unroll
    for (int off = 32; off > 0; off >>= 1) s += __shfl_down(s, off);
    __shared__ float red[4];
    if ((t & 63) == 0) red[t >> 6] = s;
    __syncthreads();
    float tot = red[0] + red[1] + red[2] + red[3];
    float inv = rsqrtf(tot * (1.0f / (float)HID) + 1e-6f);
    f32x4 wa = *(const f32x4*)(wgt + t * 8);
    f32x4 wb = *(const f32x4*)(wgt + t * 8 + 4);
    unsigned int pk[4];
#pragma unroll
    for (int i = 0; i < 2; ++i) {
        pk[i]     = (unsigned)f2bf_bits(a[2*i] * inv * wa[2*i]) |
                    ((unsigned)f2bf_bits(a[2*i+1] * inv * wa[2*i+1]) << 16);
        pk[i + 2] = (unsigned)f2bf_bits(b[2*i] * inv * wb[2*i]) |
                    ((unsigned)f2bf_bits(b[2*i+1] * inv * wb[2*i+1]) << 16);
    }
    u32x4 ov; ov[0] = pk[0]; ov[1] = pk[1]; ov[2] = pk[2]; ov[3] = pk[3];
    *(u32x4*)(out + (size_t)row * HID + t * 8) = ov;
}

// ---- fused: x1 = x + p0..p3 (f16 partials); out x1 (f32) + rmsnorm(x1) (bf16) ----
__global__ __launch_bounds__(256)
void res_rms(const float* __restrict__ x, const _Float16* __restrict__ p,
             const float* __restrict__ wgt, float* __restrict__ x1out,
             unsigned short* __restrict__ xnout, int n)
{
    int row = blockIdx.x;
    int t = threadIdx.x;
    int base = row * HID + t * 8;
    f32x4 a = *(const f32x4*)(x + base);
    f32x4 b = *(const f32x4*)(x + base + 4);
#pragma unroll
    for (int z = 0; z < 4; ++z) {
        f16x4 h0 = *(const f16x4*)(p + (size_t)z * n + base);
        f16x4 h1 = *(const f16x4*)(p + (size_t)z * n + base + 4);
#pragma unroll
        for (int j = 0; j < 4; ++j) { a[j] += (float)h0[j]; b[j] += (float)h1[j]; }
    }
    *(f32x4*)(x1out + base) = a;
    *(f32x4*)(x1out + base + 4) = b;
    float s = 0.f;
#pragma unroll
    for (int i = 0; i < 4; ++i) s += a[i] * a[i] + b[i] * b[i];
#pragma unroll
    for (int off = 32; off > 0; off >>= 1) s += __shfl_down(s, off);
    __shared__ float red[4];
    if ((t & 63) == 0) red[t >> 6] = s;
    __syncthreads();
    float tot = red[0] + red[1] + red[2] + red[3];
    float inv = rsqrtf(tot * (1.0f / (float)HID) + 1e-6f);
    f32x4 wa = *(const f32x4*)(wgt + t * 8);
    f32x4 wb = *(const f32x4*)(wgt + t * 8 + 4);
    unsigned int pk[4];
#pragma unroll
    for (int i = 0; i < 2; ++i) {
        pk[i]     = (unsigned)f2bf_bits(a[2*i] * inv * wa[2*i]) |
                    ((unsigned)f2bf_bits(a[2*i+1] * inv * wa[2*i+1]) << 16);
        pk[i + 2] = (unsigned)f2bf_bits(b[2*i] * inv * wb[2*i]) |
                    ((unsigned)f2bf_bits(b[2*i+1] * inv * wb[2*i+1]) << 16);
    }
    u32x4 ov; ov[0] = pk[0]; ov[1] = pk[1]; ov[2] = pk[2]; ov[3] = pk[3];
    *(u32x4*)(xnout + base) = ov;
}

// ------------- transpose + convert: f32 [K][N] -> bf16 [N][K] -------------
__global__ __launch_bounds__(256)
void transpose_cvt(const float* __restrict__ in, unsigned short* __restrict__ out,
                   int K, int N)
{
    __shared__ unsigned short tile[64 * 65];
    int kb = blockIdx.y * 64, nb = blockIdx.x * 64;
    int t = threadIdx.x;
    int r = t >> 2, c0 = (t & 3) * 16;
    const float* src = in + (size_t)(kb + r) * N + nb + c0;
#pragma unroll
    for (int j = 0; j < 4; ++j) {
        f32x4 v = *(const f32x4*)(src + j * 4);
#pragma unroll
        for (int i = 0; i < 4; ++i)
            tile[r * 65 + c0 + j * 4 + i] = f2bf_bits(v[i]);
    }
    __syncthreads();
    unsigned short e[16];
#pragma unroll
    for (int j = 0; j < 16; ++j) e[j] = tile[(c0 + j) * 65 + r];
    u32x4 o0, o1;
#pragma unroll
    for (int j = 0; j < 4; ++j) {
        o0[j] = (unsigned)e[2*j] | ((unsigned)e[2*j+1] << 16);
        o1[j] = (unsigned)e[8 + 2*j] | ((unsigned)e[8 + 2*j+1] << 16);
    }
    unsigned short* dst = out + (size_t)(nb + r) * K + kb + c0;
    *(u32x4*)(dst) = o0;
    *(u32x4*)(dst + 8) = o1;
}

// ---- fused split-K reduce + rope + bf16 convert (vectorized): partials -> qkv ----
__global__ __launch_bounds__(256)
void reduce_rope(const _Float16* __restrict__ p, const float* __restrict__ sin_t,
                 const float* __restrict__ cos_t, unsigned short* __restrict__ qkv,
                 int n)
{
    int s = blockIdx.x;
    size_t base = (size_t)s * 3072;
    for (int it = threadIdx.x; it < (NHEAD + NKVH) * 16; it += 256) {
        int slot = it >> 4, dp = (it & 15) * 2;
        int col = slot * 64 + dp;
        f16x2 a0 = *(const f16x2*)(p + base + col);
        f16x2 b0 = *(const f16x2*)(p + (size_t)n + base + col);
        f16x2 a1 = *(const f16x2*)(p + base + col + 32);
        f16x2 b1 = *(const f16x2*)(p + (size_t)n + base + col + 32);
        f32x2 cc = *(const f32x2*)(cos_t + s * 32 + dp);
        f32x2 ss = *(const f32x2*)(sin_t + s * 32 + dp);
        float x0a = (float)a0[0] + (float)b0[0];
        float x0b = (float)a0[1] + (float)b0[1];
        float x1a = (float)a1[0] + (float)b1[0];
        float x1b = (float)a1[1] + (float)b1[1];
        unsigned lo = (unsigned)f2bf_bits(x0a * cc[0] - x1a * ss[0]) |
                      ((unsigned)f2bf_bits(x0b * cc[1] - x1b * ss[1]) << 16);
        unsigned hi = (unsigned)f2bf_bits(x0a * ss[0] + x1a * cc[0]) |
                      ((unsigned)f2bf_bits(x0b * ss[1] + x1b * cc[1]) << 16);
        *(unsigned*)(qkv + base + col)      = lo;
        *(unsigned*)(qkv + base + col + 32) = hi;
    }
    for (int it = threadIdx.x; it < (NKVH * HDIM) / 8; it += 256) {
        int col = 2560 + it * 8;
        f16x4 a0 = *(const f16x4*)(p + base + col);
        f16x4 a1 = *(const f16x4*)(p + base + col + 4);
        f16x4 b0 = *(const f16x4*)(p + (size_t)n + base + col);
        f16x4 b1 = *(const f16x4*)(p + (size_t)n + base + col + 4);
        u32x4 ov;
#pragma unroll
        for (int j = 0; j < 2; ++j) {
            ov[j] = (unsigned)f2bf_bits((float)a0[2*j] + (float)b0[2*j]) |
                    ((unsigned)f2bf_bits((float)a0[2*j+1] + (float)b0[2*j+1]) << 16);
            ov[2 + j] = (unsigned)f2bf_bits((float)a1[2*j] + (float)b1[2*j]) |
                        ((unsigned)f2bf_bits((float)a1[2*j+1] + (float)b1[2*j+1]) << 16);
        }
        *(u32x4*)(qkv + base + col) = ov;
    }
}

// ---- V^T prepass: qkv v-slice [S][kvh*64+d] -> vT[kvh][d][S] (slot-swizzled) ----
__global__ __launch_bounds__(256)
void transpose_v(const unsigned short* __restrict__ qkv, unsigned short* __restrict__ vT)
{
    __shared__ unsigned short tile[64][80];
    int kb = blockIdx.x * 64, kvh = blockIdx.y;
    int t = threadIdx.x;
    int r = t >> 2, c0 = (t & 3) * 16;
    const unsigned short* src = qkv + (size_t)(kb + r) * 3072 + 2560 + kvh * 64 + c0;
    u32x4 v0 = *(const u32x4*)(src);
    u32x4 v1 = *(const u32x4*)(src + 8);
    *(u32x4*)&tile[r][c0] = v0;
    *(u32x4*)&tile[r][c0 + 8] = v1;
    __syncthreads();
    int d = t >> 2, k0 = (t & 3) * 16;
    unsigned short e[16];
#pragma unroll
    for (int j = 0; j < 16; ++j) e[j] = tile[k0 + j][d];
    u32x4 o0, o1;
#pragma unroll
    for (int j = 0; j < 4; ++j) {
        o0[j] = (unsigned)e[2*j] | ((unsigned)e[2*j+1] << 16);
        o1[j] = (unsigned)e[8 + 2*j] | ((unsigned)e[8 + 2*j+1] << 16);
    }
    int s0 = ((k0 >> 3) ^ (d & 7)) & 7;
    int s1 = (((k0 >> 3) + 1) ^ (d & 7)) & 7;
    unsigned short* dst = vT + ((size_t)kvh * 64 + d) * 2048 + kb;
    *(u32x4*)(dst + s0 * 8) = o0;
    *(u32x4*)(dst + s1 * 8) = o1;
}

// ---- 256x256 GEMM, merged phases + register-pipelined fragment reads ----
template <int KK>
__device__ __forceinline__ void phaseP(u16* lds, int cur, f32x4 (&acc)[8][4],
                                       u32x4 (&rcur)[12], u32x4 (&rnext)[12],
                                       int aoff, int boff,
                                       const u16* Asrc, const u16* Bsrc,
                                       int lda, int kt_stage,
                                       int dst0, int dst1)
{
    asm volatile("s_waitcnt vmcnt(4)" ::: "memory");
    {   // prefetch fragments for NEXT phase
        int nbuf = (KK == 0) ? cur : (cur ^ 1);
        int nslot = (KK == 0) ? 2 : 0;
        const u16* ah = lds + (nbuf * 4 + nslot) * 8192 + aoff;
        const u16* bh = lds + (nbuf * 4 + nslot + 1) * 8192 + boff;
#pragma unroll
        for (int m = 0; m < 8; ++m)
            rnext[m] = *(const u32x4*)(ah + (m >> 2) * 2048 + (m & 3) * 512);
#pragma unroll
        for (int ni = 0; ni < 4; ++ni)
            rnext[8 + ni] = *(const u32x4*)(bh + ni * 512);
    }
    {   // stage one k-half of a future tile
        const u16* sa = Asrc + (size_t)kt_stage * 64 + (KK == 0 ? 32 : 0);
        const u16* sb = Bsrc + (size_t)kt_stage * 64 + (KK == 0 ? 32 : 0);
        int dbuf = (KK == 0) ? (cur ^ 1) : cur;
        u16* dA = lds + (dbuf * 4 + (KK == 0 ? 2 : 0)) * 8192;
        u16* dB = lds + (dbuf * 4 + (KK == 0 ? 3 : 1)) * 8192;
        gload_lds16(sa, dA + dst0);
        gload_lds16(sa + (size_t)128 * lda, dA + dst1);
        gload_lds16(sb, dB + dst0);
        gload_lds16(sb + (size_t)128 * lda, dB + dst1);
    }
    __builtin_amdgcn_sched_barrier(0);
    __builtin_amdgcn_s_setprio(1);
#pragma unroll
    for (int m = 0; m < 8; ++m)
#pragma unroll
        for (int ni = 0; ni < 4; ++ni)
            acc[m][ni] = mfma_bf16(rcur[m], rcur[8 + ni], acc[m][ni]);
    __builtin_amdgcn_s_setprio(0);
    __builtin_amdgcn_s_barrier();
}

template <int EPI>
__global__ __launch_bounds__(512, 2)
void gemm8p(const u16* __restrict__ A, const u16* __restrict__ Bt,
            void* __restrict__ outp, const void* __restrict__ auxp,
            int M, int N, int Kc, int lda)
{
    extern __shared__ u16 lds[];   // 128 KiB
    const int tid = threadIdx.x;
    const int w = tid >> 6, l = tid & 63;
    const int wm = w >> 2, wn = w & 3;
    const int l4 = l >> 4, l15 = l & 15;
    const int zb = blockIdx.y;

    int wg = blockIdx.x, nwg = gridDim.x;
    int swzb = ((nwg & 7) == 0) ? ((wg & 7) * (nwg >> 3) + (wg >> 3)) : wg;
    int rbs = M >> 8;
    int rb = swzb % rbs, cb = swzb / rbs;

    const int sw = ((tid & 3) ^ ((tid >> 3) & 3)) * 8;
    const int srow = tid >> 2;
    const u16* Asrc = A + (size_t)(rb * 256 + srow) * lda + (size_t)zb * Kc + sw;
    const u16* Bsrc = Bt + (size_t)(cb * 256 + srow) * lda + (size_t)zb * Kc + sw;
    const int dst0 = tid * 8, dst1 = (512 + tid) * 8;

    const int rswz = (l15 >> 1) & 3;
    const int aoff = (wm * 128 + l15) * 32 + (l4 ^ rswz) * 8;
    const int boff = (wn * 64 + l15) * 32 + (l4 ^ rswz) * 8;

    f32x4 acc[8][4] = {};
    u32x4 rA[12], rB[12];
    const int NT = Kc >> 6;

    {
#pragma unroll
        for (int h = 0; h < 2; ++h) {
            const u16* sA = Asrc + h * 32;
            const u16* sB = Bsrc + h * 32;
            gload_lds16(sA, lds + (h * 2) * 8192 + dst0);
            gload_lds16(sA + (size_t)128 * lda, lds + (h * 2) * 8192 + dst1);
            gload_lds16(sB, lds + (h * 2 + 1) * 8192 + dst0);
            gload_lds16(sB + (size_t)128 * lda, lds + (h * 2 + 1) * 8192 + dst1);
        }
        int t1 = (NT > 1) ? 1 : 0;
        const u16* sA = Asrc + (size_t)t1 * 64;
        const u16* sB = Bsrc + (size_t)t1 * 64;
        gload_lds16(sA, lds + (4 + 0) * 8192 + dst0);
        gload_lds16(sA + (size_t)128 * lda, lds + (4 + 0) * 8192 + dst1);
        gload_lds16(sB, lds + (4 + 1) * 8192 + dst0);
        gload_lds16(sB + (size_t)128 * lda, lds + (4 + 1) * 8192 + dst1);
    }
    asm volatile("s_waitcnt vmcnt(8)" ::: "memory");
    __builtin_amdgcn_s_barrier();
    {   // pre-read phase-(0,0) fragments (buf0 slots 0,1)
        const u16* ah = lds + aoff;
        const u16* bh = lds + 8192 + boff;
#pragma unroll
        for (int m = 0; m < 8; ++m)
            rA[m] = *(const u32x4*)(ah + (m >> 2) * 2048 + (m & 3) * 512);
#pragma unroll
        for (int ni = 0; ni < 4; ++ni)
            rA[8 + ni] = *(const u32x4*)(bh + ni * 512);
    }

    for (int t = 0; t < NT; ++t) {
        int cur = t & 1;
        int k1 = (t + 1 < NT) ? t + 1 : 0;
        int k2 = (t + 2 < NT) ? t + 2 : 0;
        phaseP<0>(lds, cur, acc, rA, rB, aoff, boff, Asrc, Bsrc, lda, k1, dst0, dst1);
        phaseP<1>(lds, cur, acc, rB, rA, aoff, boff, Asrc, Bsrc, lda, k2, dst0, dst1);
    }
    asm volatile("s_waitcnt vmcnt(0)" ::: "memory");

    int row0 = rb * 256 + wm * 128 + l4 * 4;
    int col0 = cb * 256 + wn * 64 + l15;
#pragma unroll
    for (int mi = 0; mi < 8; ++mi) {
#pragma unroll
        for (int ni = 0; ni < 4; ++ni) {
#pragma unroll
            for (int r = 0; r < 4; ++r) {
                int row = row0 + mi * 16 + r;
                int col = col0 + ni * 16;
                size_t idx = (size_t)row * N + col;
                float v = acc[mi][ni][r];
                if (EPI == 1) {
                    float sv = v / (1.0f + __expf(-v));
                    ((unsigned short*)outp)[idx] = f2bf_bits(sv);
                } else if (EPI == 2) {
                    float gv = bf2f(((const unsigned short*)auxp)[idx]);
                    ((unsigned short*)outp)[idx] = f2bf_bits(v * gv);
                } else {
                    ((_Float16*)outp)[(size_t)zb * M * N + idx] = (_Float16)v;
                }
            }
        }
    }
}

// -------- fused gate+up, merged phases + register-pipelined reads --------
template <int KK>
__device__ __forceinline__ void phasePgu(u16* lds, int cur, f32x4 (&acc)[8][4],
                                         u32x4 (&rcur)[12], u32x4 (&rnext)[12],
                                         int aoff, int boffg, int boffu,
                                         const u16* Asrc, const u16* Bg, const u16* Bu,
                                         int lda, int kt_stage,
                                         int dst0, int dst1)
{
    asm volatile("s_waitcnt vmcnt(4)" ::: "memory");
    {
        int nbuf = (KK == 0) ? cur : (cur ^ 1);
        int nslot = (KK == 0) ? 2 : 0;
        const u16* ah = lds + (nbuf * 4 + nslot) * 8192 + aoff;
        const u16* bh = lds + (nbuf * 4 + nslot + 1) * 8192;
#pragma unroll
        for (int m = 0; m < 8; ++m)
            rnext[m] = *(const u32x4*)(ah + (m >> 2) * 2048 + (m & 3) * 512);
#pragma unroll
        for (int ni = 0; ni < 2; ++ni) {
            rnext[8 + ni]  = *(const u32x4*)(bh + boffg + ni * 512);
            rnext[10 + ni] = *(const u32x4*)(bh + boffu + ni * 512);
        }
    }
    {
        int koff = (KK == 0 ? 32 : 0);
        const u16* sa = Asrc + (size_t)kt_stage * 64 + koff;
        int dbuf = (KK == 0) ? (cur ^ 1) : cur;
        u16* dA = lds + (dbuf * 4 + (KK == 0 ? 2 : 0)) * 8192;
        u16* dB = lds + (dbuf * 4 + (KK == 0 ? 3 : 1)) * 8192;
        gload_lds16(sa, dA + dst0);
        gload_lds16(sa + (size_t)128 * lda, dA + dst1);
        gload_lds16(Bg + (size_t)kt_stage * 64 + koff, dB + dst0);
        gload_lds16(Bu + (size_t)kt_stage * 64 + koff, dB + dst1);
    }
    __builtin_amdgcn_sched_barrier(0);
    __builtin_amdgcn_s_setprio(1);
#pragma unroll
    for (int m = 0; m < 8; ++m)
#pragma unroll
        for (int ni = 0; ni < 4; ++ni)
            acc[m][ni] = mfma_bf16(rcur[m], rcur[8 + ni], acc[m][ni]);
    __builtin_amdgcn_s_setprio(0);
    __builtin_amdgcn_s_barrier();
}

__global__ __launch_bounds__(512, 2)
void gemm8p_gu(const u16* __restrict__ A, const u16* __restrict__ WgT,
               const u16* __restrict__ WuT, unsigned short* __restrict__ outp,
               int M, int Nfull, int K)
{
    extern __shared__ u16 lds[];   // 128 KiB
    const int tid = threadIdx.x;
    const int w = tid >> 6, l = tid & 63;
    const int wm = w >> 2, wn = w & 3;
    const int l4 = l >> 4, l15 = l & 15;

    int wg = blockIdx.x, nwg = gridDim.x;
    int swzb = ((nwg & 7) == 0) ? ((wg & 7) * (nwg >> 3) + (wg >> 3)) : wg;
    int rbs = M >> 8;
    int rb = swzb % rbs, cb = swzb / rbs;

    const int sw = ((tid & 3) ^ ((tid >> 3) & 3)) * 8;
    const int srow = tid >> 2;
    const u16* Asrc = A + (size_t)(rb * 256 + srow) * K + sw;
    const u16* Bg = WgT + (size_t)(cb * 128 + srow) * K + sw;
    const u16* Bu = WuT + (size_t)(cb * 128 + srow) * K + sw;
    const int dst0 = tid * 8, dst1 = (512 + tid) * 8;

    const int rswz = (l15 >> 1) & 3;
    const int aoff  = (wm * 128 + l15) * 32 + (l4 ^ rswz) * 8;
    const int boffg = (wn * 32 + l15) * 32 + (l4 ^ rswz) * 8;
    const int boffu = (128 + wn * 32 + l15) * 32 + (l4 ^ rswz) * 8;

    f32x4 acc[8][4] = {};
    u32x4 rA[12], rB[12];
    const int NT = K >> 6;

    {
#pragma unroll
        for (int h = 0; h < 2; ++h) {
            const u16* sA = Asrc + h * 32;
            gload_lds16(sA, lds + (h * 2) * 8192 + dst0);
            gload_lds16(sA + (size_t)128 * K, lds + (h * 2) * 8192 + dst1);
            gload_lds16(Bg + h * 32, lds + (h * 2 + 1) * 8192 + dst0);
            gload_lds16(Bu + h * 32, lds + (h * 2 + 1) * 8192 + dst1);
        }
        const u16* sA = Asrc + 64;
        gload_lds16(sA, lds + (4 + 0) * 8192 + dst0);
        gload_lds16(sA + (size_t)128 * K, lds + (4 + 0) * 8192 + dst1);
        gload_lds16(Bg + 64, lds + (4 + 1) * 8192 + dst0);
        gload_lds16(Bu + 64, lds + (4 + 1) * 8192 + dst1);
    }
    asm volatile("s_waitcnt vmcnt(8)" ::: "memory");
    __builtin_amdgcn_s_barrier();
    {
        const u16* ah = lds + aoff;
        const u16* bh = lds + 8192;
#pragma unroll
        for (int m = 0; m < 8; ++m)
            rA[m] = *(const u32x4*)(ah + (m >> 2) * 2048 + (m & 3) * 512);
#pragma unroll
        for (int ni = 0; ni < 2; ++ni) {
            rA[8 + ni]  = *(const u32x4*)(bh + boffg + ni * 512);
            rA[10 + ni] = *(const u32x4*)(bh + boffu + ni * 512);
        }
    }

    for (int t = 0; t < NT; ++t) {
        int cur = t & 1;
        int k1 = (t + 1 < NT) ? t + 1 : 0;
        int k2 = (t + 2 < NT) ? t + 2 : 0;
        phasePgu<0>(lds, cur, acc, rA, rB, aoff, boffg, boffu, Asrc, Bg, Bu, K, k1, dst0, dst1);
        phasePgu<1>(lds, cur, acc, rB, rA, aoff, boffg, boffu, Asrc, Bg, Bu, K, k2, dst0, dst1);
    }
    asm volatile("s_waitcnt vmcnt(0)" ::: "memory");

    int row0 = rb * 256 + wm * 128 + l4 * 4;
    int col0 = cb * 128 + wn * 32 + l15;
#pragma unroll
    for (int mi = 0; mi < 8; ++mi) {
#pragma unroll
        for (int ni = 0; ni < 2; ++ni) {
#pragma unroll
            for (int r = 0; r < 4; ++r) {
                int row = row0 + mi * 16 + r;
                int col = col0 + ni * 16;
                float gv = acc[mi][ni][r];
                float uv = acc[mi][ni + 2][r];
                float sv = gv / (1.0f + __expf(-gv)) * uv;
                outp[(size_t)row * Nfull + col] = f2bf_bits(sv);
            }
        }
    }
}

// ---------------- split-K reduce: out += p0+p1+p2+p3 (f16 partials) ----------------
__global__ __launch_bounds__(256)
void reduce_add4(float* __restrict__ out, const _Float16* __restrict__ p, int n)
{
    int i = (blockIdx.x * 256 + threadIdx.x) * 4;
    f32x4 a = *(const f32x4*)(out + i);
#pragma unroll
    for (int z = 0; z < 4; ++z) {
        f16x4 h = *(const f16x4*)(p + (size_t)z * n + i);
#pragma unroll
        for (int j = 0; j < 4; ++j) a[j] += (float)h[j];
    }
    *(f32x4*)(out + i) = a;
}

// ------- causal GQA flash attention (swapped QK^T, in-register softmax, T5, paired) -------
__global__ __launch_bounds__(256)
void attn_fwd(const unsigned short* __restrict__ qkv,
              const unsigned short* __restrict__ vT,
              unsigned short* __restrict__ out)
{
    int p = blockIdx.x, h = blockIdx.y, kvh = h >> 2;
    int t = threadIdx.x, w = t >> 6, l = t & 63;
    int l4 = l >> 4, l15 = l & 15;
    __shared__ unsigned short Ks[2][64 * 64];
    __shared__ unsigned short Vs[2][64 * 64];

    const unsigned short* Kg = qkv + HID + kvh * 64;
    const unsigned short* Vg = vT + (size_t)kvh * 64 * 2048;

    int ch0 = w * 2, ch1 = w * 2 + 1;
    int rsub = l >> 3;
    int ksw = ((l & 7) ^ (rsub & 7)) * 8;
    int vcol = (l & 7) * 8;
    int sw0 = (l4 ^ (l15 & 7)) * 8;
    int sw1 = ((l4 | 4) ^ (l15 & 7)) * 8;
    int srcA = ((l >> 4) & 1) * 32 + l15;
    int srcB = srcA + 16;
    bool hi32 = (l & 32) != 0;

#define STAGE_KV(buf, kt)                                                         \
    {                                                                             \
        gload_lds16(Kg + (size_t)((kt) * 64 + ch0 * 8 + rsub) * 3072 + ksw,       \
                    &Ks[buf][ch0 * 512]);                                         \
        gload_lds16(Kg + (size_t)((kt) * 64 + ch1 * 8 + rsub) * 3072 + ksw,       \
                    &Ks[buf][ch1 * 512]);                                         \
        gload_lds16(Vg + (size_t)(ch0 * 8 + rsub) * 2048 + (kt) * 64 + vcol,      \
                    &Vs[buf][ch0 * 512]);                                         \
        gload_lds16(Vg + (size_t)(ch1 * 8 + rsub) * 2048 + (kt) * 64 + vcol,      \
                    &Vs[buf][ch1 * 512]);                                         \
    }

    const float SC2 = 0.18033688f;
    const float THR = 44.36f;
    const float BIG = -3.0e38f;

    for (int half = 0; half < 2; ++half) {
        int qb = half ? (31 - p) : p;
        int qrow0 = qb * 64 + w * 16;
        STAGE_KV(0, 0);
        const unsigned short* qg = qkv + (size_t)(qrow0 + l15) * 3072 + h * 64 + l4 * 8;
        u32x4 aq0 = *(const u32x4*)(qg);
        u32x4 aq1 = *(const u32x4*)(qg + 32);
        f32x4 o[4] = {};
        float m = BIG, ls = 0.f;
        __syncthreads();
        int cur = 0;
        for (int kt = 0; kt <= qb; ++kt) {
            if (kt < qb) STAGE_KV(cur ^ 1, kt + 1);
            f32x4 sc[4];
            __builtin_amdgcn_s_setprio(1);
#pragma unroll
            for (int n = 0; n < 4; ++n) {
                const unsigned short* kb_ = &Ks[cur][(n * 16 + l15) * 64];
                u32x4 b0 = *(const u32x4*)(kb_ + sw0);
                u32x4 b1 = *(const u32x4*)(kb_ + sw1);
                f32x4 z = {};
                z = mfma_bf16(b0, aq0, z);
                z = mfma_bf16(b1, aq1, z);
                sc[n] = z;
            }
            __builtin_amdgcn_s_setprio(0);
            if (kt == qb) {
                int qloc = w * 16 + l15;
#pragma unroll
                for (int n = 0; n < 4; ++n)
#pragma unroll
                    for (int r = 0; r < 4; ++r)
                        if (n * 16 + l4 * 4 + r > qloc) sc[n][r] = BIG;
            }
            float rmax = BIG;
#pragma unroll
            for (int n = 0; n < 4; ++n)
#pragma unroll
                for (int r = 0; r < 4; ++r) rmax = fmaxf(rmax, sc[n][r]);
            rmax = fmaxf(rmax, __shfl_xor(rmax, 16));
            rmax = fmaxf(rmax, __shfl_xor(rmax, 32));
            if (__ballot(rmax - m > THR)) {
                float mn = fmaxf(m, rmax);
                float al = __builtin_exp2f((m - mn) * SC2);
                m = mn;
                ls *= al;
#pragma unroll
                for (int nd = 0; nd < 4; ++nd)
#pragma unroll
                    for (int r = 0; r < 4; ++r) o[nd][r] *= al;
            }
            float ms = m * SC2, rs = 0.f;
#pragma unroll
            for (int n = 0; n < 4; ++n)
#pragma unroll
                for (int r = 0; r < 4; ++r) {
                    float pe = __builtin_exp2f(__builtin_fmaf(sc[n][r], SC2, -ms));
                    sc[n][r] = pe;
                    rs += pe;
                }
            rs += __shfl_xor(rs, 16);
            rs += __shfl_xor(rs, 32);
            ls += rs;
            unsigned pk0[2], pk1[2], pk2[2], pk3[2];
#pragma unroll
            for (int rr = 0; rr < 2; ++rr) {
                pk0[rr] = cvt_pk_bf16(sc[0][2*rr], sc[0][2*rr+1]);
                pk1[rr] = cvt_pk_bf16(sc[1][2*rr], sc[1][2*rr+1]);
                pk2[rr] = cvt_pk_bf16(sc[2][2*rr], sc[2][2*rr+1]);
                pk3[rr] = cvt_pk_bf16(sc[3][2*rr], sc[3][2*rr+1]);
            }
            u32x4 W1, W2;
            {
                unsigned a0, a1;
                a0 = __shfl(pk0[0], srcA); a1 = __shfl(pk1[0], srcA); W1[0] = hi32 ? a1 : a0;
                a0 = __shfl(pk0[1], srcA); a1 = __shfl(pk1[1], srcA); W1[1] = hi32 ? a1 : a0;
                a0 = __shfl(pk0[0], srcB); a1 = __shfl(pk1[0], srcB); W1[2] = hi32 ? a1 : a0;
                a0 = __shfl(pk0[1], srcB); a1 = __shfl(pk1[1], srcB); W1[3] = hi32 ? a1 : a0;
                a0 = __shfl(pk2[0], srcA); a1 = __shfl(pk3[0], srcA); W2[0] = hi32 ? a1 : a0;
                a0 = __shfl(pk2[1], srcA); a1 = __shfl(pk3[1], srcA); W2[1] = hi32 ? a1 : a0;
                a0 = __shfl(pk2[0], srcB); a1 = __shfl(pk3[0], srcB); W2[2] = hi32 ? a1 : a0;
                a0 = __shfl(pk2[1], srcB); a1 = __shfl(pk3[1], srcB); W2[3] = hi32 ? a1 : a0;
            }
            __builtin_amdgcn_s_setprio(1);
#pragma unroll
            for (int nd = 0; nd < 4; ++nd) {
                const unsigned short* vb = &Vs[cur][(nd * 16 + l15) * 64];
                u32x4 bv0 = *(const u32x4*)(vb + sw0);
                u32x4 bv1 = *(const u32x4*)(vb + sw1);
                o[nd] = mfma_bf16(bv0, W1, o[nd]);
                o[nd] = mfma_bf16(bv1, W2, o[nd]);
            }
            __builtin_amdgcn_s_setprio(0);
            __syncthreads();
            cur ^= 1;
        }
#undef STAGE_KV
        float linv = 1.0f / ls;
        unsigned short* orow = out + (size_t)(qrow0 + l15) * HID + h * 64 + l4 * 4;
#pragma unroll
        for (int nd = 0; nd < 4; ++nd) {
            u32x2 wv;
            wv[0] = cvt_pk_bf16(o[nd][0] * linv, o[nd][1] * linv);
            wv[1] = cvt_pk_bf16(o[nd][2] * linv, o[nd][3] * linv);
            *(u32x2*)(orow + nd * 16) = wv;
        }
    }
}

extern "C" void kernel_launch(void* const* d_in, const int* in_sizes, int n_in,
                              void* d_out, int out_size, void* d_ws, size_t ws_size,
                              hipStream_t stream)
{
    const float* x     = (const float*)d_in[0];
    const float* sin_t = (const float*)d_in[1];
    const float* cos_t = (const float*)d_in[2];
    const float* ln1w  = (const float*)d_in[3];
    const float* ln2w  = (const float*)d_in[4];
    const float* wq    = (const float*)d_in[5];
    const float* wk    = (const float*)d_in[6];
    const float* wv    = (const float*)d_in[7];
    const float* wo    = (const float*)d_in[8];
    const float* wg    = (const float*)d_in[9];
    const float* wu    = (const float*)d_in[10];
    const float* wd    = (const float*)d_in[11];
    float* out = (float*)d_out;

    char* ws = (char*)d_ws;
    if (ws_size < 113246208u) return;
    unsigned short* wT    = (unsigned short*)(ws);                 // [0, 33.5MB)
    unsigned short* xn    = (unsigned short*)(ws + 33554432u);     // [33.5, 41.9MB)
    unsigned short* qkv   = (unsigned short*)(ws + 41943040u);     // [41.9, 54.5MB) attn window
    unsigned short* attn  = (unsigned short*)(ws + 54525952u);     // [54.5, 62.9MB)
    unsigned short* vT    = (unsigned short*)(ws + 62914560u);     // [62.9, 65.0MB)
    unsigned short* wuT   = (unsigned short*)(ws + 41943040u);     // [41.9, 75.4MB) MLP window
    _Float16*       part  = (_Float16*)(ws + 41943040u);           // [41.9, 75.4MB) down window
    unsigned short* g     = (unsigned short*)(ws + 79691776u);     // [79.7, 113.2MB)
    _Float16*       opart = (_Float16*)(ws + 79691776u);           // o-proj window
    _Float16*       qpart = (_Float16*)(ws + 79691776u);           // qkv-proj window

    hipFuncSetAttribute(reinterpret_cast<const void*>(&gemm8p<5>),
                        hipFuncAttributeMaxDynamicSharedMemorySize, 131072);
    hipFuncSetAttribute(reinterpret_cast<const void*>(&gemm8p_gu),
                        hipFuncAttributeMaxDynamicSharedMemorySize, 131072);

    // x -> rmsnorm -> xn (bf16)
    rmsnorm_k<<<S_LEN, 256, 0, stream>>>(x, ln1w, xn);

    // wq|wk|wv -> wT as [3072][2048] transposed bf16
    transpose_cvt<<<dim3(32, 32), 256, 0, stream>>>(wq, wT, 2048, 2048);
    transpose_cvt<<<dim3(8, 32), 256, 0, stream>>>(wk, wT + (size_t)2048 * 2048, 2048, 512);
    transpose_cvt<<<dim3(8, 32), 256, 0, stream>>>(wv, wT + (size_t)2560 * 2048, 2048, 512);

    // qkv partials = xn @ [wq wk wv]   [split-K=2, f16 partials]
    gemm8p<5><<<dim3(96, 2), 512, 131072, stream>>>(xn, wT, qpart, nullptr, 2048, 3072, 1024, 2048);

    // fused: qkv = reduce(partials) + rope(q,k) + bf16 convert  [vectorized]
    reduce_rope<<<S_LEN, 256, 0, stream>>>(qpart, sin_t, cos_t, qkv, 6291456);

    // v -> vT (swizzled)
    transpose_v<<<dim3(32, 8), 256, 0, stream>>>(qkv, vT);

    // attention (paired q-tiles: blocks do exactly 33 kv-tiles each)
    attn_fwd<<<dim3(16, 32), 256, 0, stream>>>(qkv, vT, attn);

    // o-proj: split-K=4 (f16 partials)
    transpose_cvt<<<dim3(32, 32), 256, 0, stream>>>(wo, wT, 2048, 2048);
    gemm8p<5><<<dim3(64, 4), 512, 131072, stream>>>(attn, wT, opart, nullptr, 2048, 2048, 512, 2048);

    // fused: d_out = x1 = x + Σp ; xn = rmsnorm(x1, ln2w)
    res_rms<<<S_LEN, 256, 0, stream>>>(x, opart, ln2w, out, xn, 4194304);

    // fused gate+up: g = silu(xn @ w_gate) * (xn @ w_up)
    transpose_cvt<<<dim3(128, 32), 256, 0, stream>>>(wg, wT, 2048, 8192);
    transpose_cvt<<<dim3(128, 32), 256, 0, stream>>>(wu, wuT, 2048, 8192);
    gemm8p_gu<<<dim3(512), 512, 131072, stream>>>(xn, wT, wuT, g, 2048, 8192, 2048);

    // down split-K=4 (f16 partials)
    transpose_cvt<<<dim3(32, 128), 256, 0, stream>>>(wd, wT, 8192, 2048);
    gemm8p<5><<<dim3(64, 4), 512, 131072, stream>>>(g, wT, part, nullptr, 2048, 2048, 2048, 8192);

    // d_out (holds x1) += part0+part1+part2+part3
    reduce_add4<<<4096, 256, 0, stream>>>(out, part, 4194304);
}

// Round 25
// 413.390 us; speedup vs baseline: 1.0692x; 1.0007x over previous
//
#include <hip/hip_runtime.h>
#include <hip/hip_bf16.h>

typedef float f32x4 __attribute__((ext_vector_type(4)));
typedef float f32x2 __attribute__((ext_vector_type(2)));
typedef unsigned int u32x4 __attribute__((ext_vector_type(4)));
typedef unsigned int u32x2 __attribute__((ext_vector_type(2)));
typedef _Float16 f16x4 __attribute__((ext_vector_type(4)));
typedef _Float16 f16x2 __attribute__((ext_vector_type(2)));
typedef unsigned short u16;

#define S_LEN 2048
#define HID 2048
#define NHEAD 32
#define NKVH 8
#define HDIM 64

__device__ __forceinline__ unsigned short f2bf_bits(float f) {
    unsigned int u = __builtin_bit_cast(unsigned int, f);
    unsigned int r = u + 0x7fffu + ((u >> 16) & 1u);
    return (unsigned short)(r >> 16);
}
__device__ __forceinline__ float bf2f(unsigned short b) {
    unsigned int u = ((unsigned int)b) << 16;
    return __builtin_bit_cast(float, u);
}
__device__ __forceinline__ unsigned cvt_pk_bf16(float lo, float hi) {
    unsigned d;
    asm("v_cvt_pk_bf16_f32 %0, %1, %2" : "=v"(d) : "v"(lo), "v"(hi));
    return d;
}

__device__ __forceinline__ f32x4 mfma_bf16(u32x4 a, u32x4 b, f32x4 c) {
    asm("v_mfma_f32_16x16x32_bf16 %0, %1, %2, %0" : "+v"(c) : "v"(a), "v"(b));
    return c;
}

__device__ __forceinline__ void gload_lds16(const void* g, void* l) {
    __builtin_amdgcn_global_load_lds(
        (const __attribute__((address_space(1))) void*)g,
        (__attribute__((address_space(3))) void*)l, 16, 0, 0);
}

// ---------------- RMSNorm: f32 [2048][2048] -> bf16 ----------------
__global__ __launch_bounds__(256)
void rmsnorm_k(const float* __restrict__ x, const float* __restrict__ wgt,
               unsigned short* __restrict__ out)
{
    int row = blockIdx.x;
    int t = threadIdx.x;
    const float* xr = x + (size_t)row * HID;
    f32x4 a = *(const f32x4*)(xr + t * 8);
    f32x4 b = *(const f32x4*)(xr + t * 8 + 4);
    float s = 0.f;
#pragma unroll
    for (int i = 0; i < 4; ++i) s += a[i] * a[i] + b[i] * b[i];
#pragma unroll
    for (int off = 32; off > 0; off >>= 1) s += __shfl_down(s, off);
    __shared__ float red[4];
    if ((t & 63) == 0) red[t >> 6] = s;
    __syncthreads();
    float tot = red[0] + red[1] + red[2] + red[3];
    float inv = rsqrtf(tot * (1.0f / (float)HID) + 1e-6f);
    f32x4 wa = *(const f32x4*)(wgt + t * 8);
    f32x4 wb = *(const f32x4*)(wgt + t * 8 + 4);
    unsigned int pk[4];
#pragma unroll
    for (int i = 0; i < 2; ++i) {
        pk[i]     = (unsigned)f2bf_bits(a[2*i] * inv * wa[2*i]) |
                    ((unsigned)f2bf_bits(a[2*i+1] * inv * wa[2*i+1]) << 16);
        pk[i + 2] = (unsigned)f2bf_bits(b[2*i] * inv * wb[2*i]) |
                    ((unsigned)f2bf_bits(b[2*i+1] * inv * wb[2*i+1]) << 16);
    }
    u32x4 ov; ov[0] = pk[0]; ov[1] = pk[1]; ov[2] = pk[2]; ov[3] = pk[3];
    *(u32x4*)(out + (size_t)row * HID + t * 8) = ov;
}

// ---- fused: x1 = x + p0..p3 (f16 partials); out x1 (f32) + rmsnorm(x1) (bf16) ----
__global__ __launch_bounds__(256)
void res_rms(const float* __restrict__ x, const _Float16* __restrict__ p,
             const float* __restrict__ wgt, float* __restrict__ x1out,
             unsigned short* __restrict__ xnout, int n)
{
    int row = blockIdx.x;
    int t = threadIdx.x;
    int base = row * HID + t * 8;
    f32x4 a = *(const f32x4*)(x + base);
    f32x4 b = *(const f32x4*)(x + base + 4);
#pragma unroll
    for (int z = 0; z < 4; ++z) {
        f16x4 h0 = *(const f16x4*)(p + (size_t)z * n + base);
        f16x4 h1 = *(const f16x4*)(p + (size_t)z * n + base + 4);
#pragma unroll
        for (int j = 0; j < 4; ++j) { a[j] += (float)h0[j]; b[j] += (float)h1[j]; }
    }
    *(f32x4*)(x1out + base) = a;
    *(f32x4*)(x1out + base + 4) = b;
    float s = 0.f;
#pragma unroll
    for (int i = 0; i < 4; ++i) s += a[i] * a[i] + b[i] * b[i];
#pragma unroll
    for (int off = 32; off > 0; off >>= 1) s += __shfl_down(s, off);
    __shared__ float red[4];
    if ((t & 63) == 0) red[t >> 6] = s;
    __syncthreads();
    float tot = red[0] + red[1] + red[2] + red[3];
    float inv = rsqrtf(tot * (1.0f / (float)HID) + 1e-6f);
    f32x4 wa = *(const f32x4*)(wgt + t * 8);
    f32x4 wb = *(const f32x4*)(wgt + t * 8 + 4);
    unsigned int pk[4];
#pragma unroll
    for (int i = 0; i < 2; ++i) {
        pk[i]     = (unsigned)f2bf_bits(a[2*i] * inv * wa[2*i]) |
                    ((unsigned)f2bf_bits(a[2*i+1] * inv * wa[2*i+1]) << 16);
        pk[i + 2] = (unsigned)f2bf_bits(b[2*i] * inv * wb[2*i]) |
                    ((unsigned)f2bf_bits(b[2*i+1] * inv * wb[2*i+1]) << 16);
    }
    u32x4 ov; ov[0] = pk[0]; ov[1] = pk[1]; ov[2] = pk[2]; ov[3] = pk[3];
    *(u32x4*)(xnout + base) = ov;
}

// ------------- transpose + convert: f32 [K][N] -> bf16 [N][K] -------------
__global__ __launch_bounds__(256)
void transpose_cvt(const float* __restrict__ in, unsigned short* __restrict__ out,
                   int K, int N)
{
    __shared__ unsigned short tile[64 * 65];
    int kb = blockIdx.y * 64, nb = blockIdx.x * 64;
    int t = threadIdx.x;
    int r = t >> 2, c0 = (t & 3) * 16;
    const float* src = in + (size_t)(kb + r) * N + nb + c0;
#pragma unroll
    for (int j = 0; j < 4; ++j) {
        f32x4 v = *(const f32x4*)(src + j * 4);
#pragma unroll
        for (int i = 0; i < 4; ++i)
            tile[r * 65 + c0 + j * 4 + i] = f2bf_bits(v[i]);
    }
    __syncthreads();
    unsigned short e[16];
#pragma unroll
    for (int j = 0; j < 16; ++j) e[j] = tile[(c0 + j) * 65 + r];
    u32x4 o0, o1;
#pragma unroll
    for (int j = 0; j < 4; ++j) {
        o0[j] = (unsigned)e[2*j] | ((unsigned)e[2*j+1] << 16);
        o1[j] = (unsigned)e[8 + 2*j] | ((unsigned)e[8 + 2*j+1] << 16);
    }
    unsigned short* dst = out + (size_t)(nb + r) * K + kb + c0;
    *(u32x4*)(dst) = o0;
    *(u32x4*)(dst + 8) = o1;
}

// ---- fused split-K reduce + rope + bf16 convert (vectorized): partials -> qkv ----
__global__ __launch_bounds__(256)
void reduce_rope(const _Float16* __restrict__ p, const float* __restrict__ sin_t,
                 const float* __restrict__ cos_t, unsigned short* __restrict__ qkv,
                 int n)
{
    int s = blockIdx.x;
    size_t base = (size_t)s * 3072;
    for (int it = threadIdx.x; it < (NHEAD + NKVH) * 16; it += 256) {
        int slot = it >> 4, dp = (it & 15) * 2;
        int col = slot * 64 + dp;
        f16x2 a0 = *(const f16x2*)(p + base + col);
        f16x2 b0 = *(const f16x2*)(p + (size_t)n + base + col);
        f16x2 a1 = *(const f16x2*)(p + base + col + 32);
        f16x2 b1 = *(const f16x2*)(p + (size_t)n + base + col + 32);
        f32x2 cc = *(const f32x2*)(cos_t + s * 32 + dp);
        f32x2 ss = *(const f32x2*)(sin_t + s * 32 + dp);
        float x0a = (float)a0[0] + (float)b0[0];
        float x0b = (float)a0[1] + (float)b0[1];
        float x1a = (float)a1[0] + (float)b1[0];
        float x1b = (float)a1[1] + (float)b1[1];
        unsigned lo = (unsigned)f2bf_bits(x0a * cc[0] - x1a * ss[0]) |
                      ((unsigned)f2bf_bits(x0b * cc[1] - x1b * ss[1]) << 16);
        unsigned hi = (unsigned)f2bf_bits(x0a * ss[0] + x1a * cc[0]) |
                      ((unsigned)f2bf_bits(x0b * ss[1] + x1b * cc[1]) << 16);
        *(unsigned*)(qkv + base + col)      = lo;
        *(unsigned*)(qkv + base + col + 32) = hi;
    }
    for (int it = threadIdx.x; it < (NKVH * HDIM) / 8; it += 256) {
        int col = 2560 + it * 8;
        f16x4 a0 = *(const f16x4*)(p + base + col);
        f16x4 a1 = *(const f16x4*)(p + base + col + 4);
        f16x4 b0 = *(const f16x4*)(p + (size_t)n + base + col);
        f16x4 b1 = *(const f16x4*)(p + (size_t)n + base + col + 4);
        u32x4 ov;
#pragma unroll
        for (int j = 0; j < 2; ++j) {
            ov[j] = (unsigned)f2bf_bits((float)a0[2*j] + (float)b0[2*j]) |
                    ((unsigned)f2bf_bits((float)a0[2*j+1] + (float)b0[2*j+1]) << 16);
            ov[2 + j] = (unsigned)f2bf_bits((float)a1[2*j] + (float)b1[2*j]) |
                        ((unsigned)f2bf_bits((float)a1[2*j+1] + (float)b1[2*j+1]) << 16);
        }
        *(u32x4*)(qkv + base + col) = ov;
    }
}

// ---- V^T prepass: qkv v-slice [S][kvh*64+d] -> vT[kvh][d][S] (slot-swizzled) ----
__global__ __launch_bounds__(256)
void transpose_v(const unsigned short* __restrict__ qkv, unsigned short* __restrict__ vT)
{
    __shared__ unsigned short tile[64][80];
    int kb = blockIdx.x * 64, kvh = blockIdx.y;
    int t = threadIdx.x;
    int r = t >> 2, c0 = (t & 3) * 16;
    const unsigned short* src = qkv + (size_t)(kb + r) * 3072 + 2560 + kvh * 64 + c0;
    u32x4 v0 = *(const u32x4*)(src);
    u32x4 v1 = *(const u32x4*)(src + 8);
    *(u32x4*)&tile[r][c0] = v0;
    *(u32x4*)&tile[r][c0 + 8] = v1;
    __syncthreads();
    int d = t >> 2, k0 = (t & 3) * 16;
    unsigned short e[16];
#pragma unroll
    for (int j = 0; j < 16; ++j) e[j] = tile[k0 + j][d];
    u32x4 o0, o1;
#pragma unroll
    for (int j = 0; j < 4; ++j) {
        o0[j] = (unsigned)e[2*j] | ((unsigned)e[2*j+1] << 16);
        o1[j] = (unsigned)e[8 + 2*j] | ((unsigned)e[8 + 2*j+1] << 16);
    }
    int s0 = ((k0 >> 3) ^ (d & 7)) & 7;
    int s1 = (((k0 >> 3) + 1) ^ (d & 7)) & 7;
    unsigned short* dst = vT + ((size_t)kvh * 64 + d) * 2048 + kb;
    *(u32x4*)(dst + s0 * 8) = o0;
    *(u32x4*)(dst + s1 * 8) = o1;
}

// ---- 256x256 GEMM, merged phases + ds_read/MFMA interleave (no sched_barrier) ----
template <int KK>
__device__ __forceinline__ void phaseP(u16* lds, int cur, f32x4 (&acc)[8][4],
                                       u32x4 (&rcur)[12], u32x4 (&rnext)[12],
                                       int aoff, int boff,
                                       const u16* Asrc, const u16* Bsrc,
                                       int lda, int kt_stage,
                                       int dst0, int dst1)
{
    asm volatile("s_waitcnt vmcnt(4)" ::: "memory");
    {   // stage one k-half of a future tile (issue early)
        const u16* sa = Asrc + (size_t)kt_stage * 64 + (KK == 0 ? 32 : 0);
        const u16* sb = Bsrc + (size_t)kt_stage * 64 + (KK == 0 ? 32 : 0);
        int dbuf = (KK == 0) ? (cur ^ 1) : cur;
        u16* dA = lds + (dbuf * 4 + (KK == 0 ? 2 : 0)) * 8192;
        u16* dB = lds + (dbuf * 4 + (KK == 0 ? 3 : 1)) * 8192;
        gload_lds16(sa, dA + dst0);
        gload_lds16(sa + (size_t)128 * lda, dA + dst1);
        gload_lds16(sb, dB + dst0);
        gload_lds16(sb + (size_t)128 * lda, dB + dst1);
    }
    // interleave next-phase fragment reads with this phase's MFMAs
    int nbuf = (KK == 0) ? cur : (cur ^ 1);
    int nslot = (KK == 0) ? 2 : 0;
    const u16* ah = lds + (nbuf * 4 + nslot) * 8192 + aoff;
    const u16* bh = lds + (nbuf * 4 + nslot + 1) * 8192 + boff;
    __builtin_amdgcn_s_setprio(1);
#pragma unroll
    for (int m = 0; m < 8; ++m) {
        rnext[m] = *(const u32x4*)(ah + (m >> 2) * 2048 + (m & 3) * 512);
        if (m < 4)
            rnext[8 + m] = *(const u32x4*)(bh + m * 512);
#pragma unroll
        for (int ni = 0; ni < 4; ++ni)
            acc[m][ni] = mfma_bf16(rcur[m], rcur[8 + ni], acc[m][ni]);
    }
    __builtin_amdgcn_s_setprio(0);
    __builtin_amdgcn_s_barrier();
}

template <int EPI>
__global__ __launch_bounds__(512, 2)
void gemm8p(const u16* __restrict__ A, const u16* __restrict__ Bt,
            void* __restrict__ outp, const void* __restrict__ auxp,
            int M, int N, int Kc, int lda)
{
    extern __shared__ u16 lds[];   // 128 KiB
    const int tid = threadIdx.x;
    const int w = tid >> 6, l = tid & 63;
    const int wm = w >> 2, wn = w & 3;
    const int l4 = l >> 4, l15 = l & 15;
    const int zb = blockIdx.y;

    int wg = blockIdx.x, nwg = gridDim.x;
    int swzb = ((nwg & 7) == 0) ? ((wg & 7) * (nwg >> 3) + (wg >> 3)) : wg;
    int rbs = M >> 8;
    int rb = swzb % rbs, cb = swzb / rbs;

    const int sw = ((tid & 3) ^ ((tid >> 3) & 3)) * 8;
    const int srow = tid >> 2;
    const u16* Asrc = A + (size_t)(rb * 256 + srow) * lda + (size_t)zb * Kc + sw;
    const u16* Bsrc = Bt + (size_t)(cb * 256 + srow) * lda + (size_t)zb * Kc + sw;
    const int dst0 = tid * 8, dst1 = (512 + tid) * 8;

    const int rswz = (l15 >> 1) & 3;
    const int aoff = (wm * 128 + l15) * 32 + (l4 ^ rswz) * 8;
    const int boff = (wn * 64 + l15) * 32 + (l4 ^ rswz) * 8;

    f32x4 acc[8][4] = {};
    u32x4 rA[12], rB[12];
    const int NT = Kc >> 6;

    {
#pragma unroll
        for (int h = 0; h < 2; ++h) {
            const u16* sA = Asrc + h * 32;
            const u16* sB = Bsrc + h * 32;
            gload_lds16(sA, lds + (h * 2) * 8192 + dst0);
            gload_lds16(sA + (size_t)128 * lda, lds + (h * 2) * 8192 + dst1);
            gload_lds16(sB, lds + (h * 2 + 1) * 8192 + dst0);
            gload_lds16(sB + (size_t)128 * lda, lds + (h * 2 + 1) * 8192 + dst1);
        }
        int t1 = (NT > 1) ? 1 : 0;
        const u16* sA = Asrc + (size_t)t1 * 64;
        const u16* sB = Bsrc + (size_t)t1 * 64;
        gload_lds16(sA, lds + (4 + 0) * 8192 + dst0);
        gload_lds16(sA + (size_t)128 * lda, lds + (4 + 0) * 8192 + dst1);
        gload_lds16(sB, lds + (4 + 1) * 8192 + dst0);
        gload_lds16(sB + (size_t)128 * lda, lds + (4 + 1) * 8192 + dst1);
    }
    asm volatile("s_waitcnt vmcnt(8)" ::: "memory");
    __builtin_amdgcn_s_barrier();
    {   // pre-read phase-(0,0) fragments (buf0 slots 0,1)
        const u16* ah = lds + aoff;
        const u16* bh = lds + 8192 + boff;
#pragma unroll
        for (int m = 0; m < 8; ++m)
            rA[m] = *(const u32x4*)(ah + (m >> 2) * 2048 + (m & 3) * 512);
#pragma unroll
        for (int ni = 0; ni < 4; ++ni)
            rA[8 + ni] = *(const u32x4*)(bh + ni * 512);
    }

    for (int t = 0; t < NT; ++t) {
        int cur = t & 1;
        int k1 = (t + 1 < NT) ? t + 1 : 0;
        int k2 = (t + 2 < NT) ? t + 2 : 0;
        phaseP<0>(lds, cur, acc, rA, rB, aoff, boff, Asrc, Bsrc, lda, k1, dst0, dst1);
        phaseP<1>(lds, cur, acc, rB, rA, aoff, boff, Asrc, Bsrc, lda, k2, dst0, dst1);
    }
    asm volatile("s_waitcnt vmcnt(0)" ::: "memory");

    int row0 = rb * 256 + wm * 128 + l4 * 4;
    int col0 = cb * 256 + wn * 64 + l15;
#pragma unroll
    for (int mi = 0; mi < 8; ++mi) {
#pragma unroll
        for (int ni = 0; ni < 4; ++ni) {
#pragma unroll
            for (int r = 0; r < 4; ++r) {
                int row = row0 + mi * 16 + r;
                int col = col0 + ni * 16;
                size_t idx = (size_t)row * N + col;
                float v = acc[mi][ni][r];
                if (EPI == 1) {
                    float sv = v / (1.0f + __expf(-v));
                    ((unsigned short*)outp)[idx] = f2bf_bits(sv);
                } else if (EPI == 2) {
                    float gv = bf2f(((const unsigned short*)auxp)[idx]);
                    ((unsigned short*)outp)[idx] = f2bf_bits(v * gv);
                } else {
                    ((_Float16*)outp)[(size_t)zb * M * N + idx] = (_Float16)v;
                }
            }
        }
    }
}

// -------- fused gate+up, merged phases + ds_read/MFMA interleave --------
template <int KK>
__device__ __forceinline__ void phasePgu(u16* lds, int cur, f32x4 (&acc)[8][4],
                                         u32x4 (&rcur)[12], u32x4 (&rnext)[12],
                                         int aoff, int boffg, int boffu,
                                         const u16* Asrc, const u16* Bg, const u16* Bu,
                                         int lda, int kt_stage,
                                         int dst0, int dst1)
{
    asm volatile("s_waitcnt vmcnt(4)" ::: "memory");
    {
        int koff = (KK == 0 ? 32 : 0);
        const u16* sa = Asrc + (size_t)kt_stage * 64 + koff;
        int dbuf = (KK == 0) ? (cur ^ 1) : cur;
        u16* dA = lds + (dbuf * 4 + (KK == 0 ? 2 : 0)) * 8192;
        u16* dB = lds + (dbuf * 4 + (KK == 0 ? 3 : 1)) * 8192;
        gload_lds16(sa, dA + dst0);
        gload_lds16(sa + (size_t)128 * lda, dA + dst1);
        gload_lds16(Bg + (size_t)kt_stage * 64 + koff, dB + dst0);
        gload_lds16(Bu + (size_t)kt_stage * 64 + koff, dB + dst1);
    }
    int nbuf = (KK == 0) ? cur : (cur ^ 1);
    int nslot = (KK == 0) ? 2 : 0;
    const u16* ah = lds + (nbuf * 4 + nslot) * 8192 + aoff;
    const u16* bh = lds + (nbuf * 4 + nslot + 1) * 8192;
    __builtin_amdgcn_s_setprio(1);
#pragma unroll
    for (int m = 0; m < 8; ++m) {
        rnext[m] = *(const u32x4*)(ah + (m >> 2) * 2048 + (m & 3) * 512);
        if (m < 2)
            rnext[8 + m] = *(const u32x4*)(bh + boffg + m * 512);
        else if (m < 4)
            rnext[8 + m] = *(const u32x4*)(bh + boffu + (m - 2) * 512);
#pragma unroll
        for (int ni = 0; ni < 4; ++ni)
            acc[m][ni] = mfma_bf16(rcur[m], rcur[8 + ni], acc[m][ni]);
    }
    __builtin_amdgcn_s_setprio(0);
    __builtin_amdgcn_s_barrier();
}

__global__ __launch_bounds__(512, 2)
void gemm8p_gu(const u16* __restrict__ A, const u16* __restrict__ WgT,
               const u16* __restrict__ WuT, unsigned short* __restrict__ outp,
               int M, int Nfull, int K)
{
    extern __shared__ u16 lds[];   // 128 KiB
    const int tid = threadIdx.x;
    const int w = tid >> 6, l = tid & 63;
    const int wm = w >> 2, wn = w & 3;
    const int l4 = l >> 4, l15 = l & 15;

    int wg = blockIdx.x, nwg = gridDim.x;
    int swzb = ((nwg & 7) == 0) ? ((wg & 7) * (nwg >> 3) + (wg >> 3)) : wg;
    int rbs = M >> 8;
    int rb = swzb % rbs, cb = swzb / rbs;

    const int sw = ((tid & 3) ^ ((tid >> 3) & 3)) * 8;
    const int srow = tid >> 2;
    const u16* Asrc = A + (size_t)(rb * 256 + srow) * K + sw;
    const u16* Bg = WgT + (size_t)(cb * 128 + srow) * K + sw;
    const u16* Bu = WuT + (size_t)(cb * 128 + srow) * K + sw;
    const int dst0 = tid * 8, dst1 = (512 + tid) * 8;

    const int rswz = (l15 >> 1) & 3;
    const int aoff  = (wm * 128 + l15) * 32 + (l4 ^ rswz) * 8;
    const int boffg = (wn * 32 + l15) * 32 + (l4 ^ rswz) * 8;
    const int boffu = (128 + wn * 32 + l15) * 32 + (l4 ^ rswz) * 8;

    f32x4 acc[8][4] = {};
    u32x4 rA[12], rB[12];
    const int NT = K >> 6;

    {
#pragma unroll
        for (int h = 0; h < 2; ++h) {
            const u16* sA = Asrc + h * 32;
            gload_lds16(sA, lds + (h * 2) * 8192 + dst0);
            gload_lds16(sA + (size_t)128 * K, lds + (h * 2) * 8192 + dst1);
            gload_lds16(Bg + h * 32, lds + (h * 2 + 1) * 8192 + dst0);
            gload_lds16(Bu + h * 32, lds + (h * 2 + 1) * 8192 + dst1);
        }
        const u16* sA = Asrc + 64;
        gload_lds16(sA, lds + (4 + 0) * 8192 + dst0);
        gload_lds16(sA + (size_t)128 * K, lds + (4 + 0) * 8192 + dst1);
        gload_lds16(Bg + 64, lds + (4 + 1) * 8192 + dst0);
        gload_lds16(Bu + 64, lds + (4 + 1) * 8192 + dst1);
    }
    asm volatile("s_waitcnt vmcnt(8)" ::: "memory");
    __builtin_amdgcn_s_barrier();
    {
        const u16* ah = lds + aoff;
        const u16* bh = lds + 8192;
#pragma unroll
        for (int m = 0; m < 8; ++m)
            rA[m] = *(const u32x4*)(ah + (m >> 2) * 2048 + (m & 3) * 512);
#pragma unroll
        for (int ni = 0; ni < 2; ++ni) {
            rA[8 + ni]  = *(const u32x4*)(bh + boffg + ni * 512);
            rA[10 + ni] = *(const u32x4*)(bh + boffu + ni * 512);
        }
    }

    for (int t = 0; t < NT; ++t) {
        int cur = t & 1;
        int k1 = (t + 1 < NT) ? t + 1 : 0;
        int k2 = (t + 2 < NT) ? t + 2 : 0;
        phasePgu<0>(lds, cur, acc, rA, rB, aoff, boffg, boffu, Asrc, Bg, Bu, K, k1, dst0, dst1);
        phasePgu<1>(lds, cur, acc, rB, rA, aoff, boffg, boffu, Asrc, Bg, Bu, K, k2, dst0, dst1);
    }
    asm volatile("s_waitcnt vmcnt(0)" ::: "memory");

    int row0 = rb * 256 + wm * 128 + l4 * 4;
    int col0 = cb * 128 + wn * 32 + l15;
#pragma unroll
    for (int mi = 0; mi < 8; ++mi) {
#pragma unroll
        for (int ni = 0; ni < 2; ++ni) {
#pragma unroll
            for (int r = 0; r < 4; ++r) {
                int row = row0 + mi * 16 + r;
                int col = col0 + ni * 16;
                float gv = acc[mi][ni][r];
                float uv = acc[mi][ni + 2][r];
                float sv = gv / (1.0f + __expf(-gv)) * uv;
                outp[(size_t)row * Nfull + col] = f2bf_bits(sv);
            }
        }
    }
}

// ---------------- split-K reduce: out += p0+p1+p2+p3 (f16 partials) ----------------
__global__ __launch_bounds__(256)
void reduce_add4(float* __restrict__ out, const _Float16* __restrict__ p, int n)
{
    int i = (blockIdx.x * 256 + threadIdx.x) * 4;
    f32x4 a = *(const f32x4*)(out + i);
#pragma unroll
    for (int z = 0; z < 4; ++z) {
        f16x4 h = *(const f16x4*)(p + (size_t)z * n + i);
#pragma unroll
        for (int j = 0; j < 4; ++j) a[j] += (float)h[j];
    }
    *(f32x4*)(out + i) = a;
}

// ------- causal GQA flash attention (swapped QK^T, in-register softmax, T5, paired) -------
__global__ __launch_bounds__(256)
void attn_fwd(const unsigned short* __restrict__ qkv,
              const unsigned short* __restrict__ vT,
              unsigned short* __restrict__ out)
{
    int p = blockIdx.x, h = blockIdx.y, kvh = h >> 2;
    int t = threadIdx.x, w = t >> 6, l = t & 63;
    int l4 = l >> 4, l15 = l & 15;
    __shared__ unsigned short Ks[2][64 * 64];
    __shared__ unsigned short Vs[2][64 * 64];

    const unsigned short* Kg = qkv + HID + kvh * 64;
    const unsigned short* Vg = vT + (size_t)kvh * 64 * 2048;

    int ch0 = w * 2, ch1 = w * 2 + 1;
    int rsub = l >> 3;
    int ksw = ((l & 7) ^ (rsub & 7)) * 8;
    int vcol = (l & 7) * 8;
    int sw0 = (l4 ^ (l15 & 7)) * 8;
    int sw1 = ((l4 | 4) ^ (l15 & 7)) * 8;
    int srcA = ((l >> 4) & 1) * 32 + l15;
    int srcB = srcA + 16;
    bool hi32 = (l & 32) != 0;

#define STAGE_KV(buf, kt)                                                         \
    {                                                                             \
        gload_lds16(Kg + (size_t)((kt) * 64 + ch0 * 8 + rsub) * 3072 + ksw,       \
                    &Ks[buf][ch0 * 512]);                                         \
        gload_lds16(Kg + (size_t)((kt) * 64 + ch1 * 8 + rsub) * 3072 + ksw,       \
                    &Ks[buf][ch1 * 512]);                                         \
        gload_lds16(Vg + (size_t)(ch0 * 8 + rsub) * 2048 + (kt) * 64 + vcol,      \
                    &Vs[buf][ch0 * 512]);                                         \
        gload_lds16(Vg + (size_t)(ch1 * 8 + rsub) * 2048 + (kt) * 64 + vcol,      \
                    &Vs[buf][ch1 * 512]);                                         \
    }

    const float SC2 = 0.18033688f;
    const float THR = 44.36f;
    const float BIG = -3.0e38f;

    for (int half = 0; half < 2; ++half) {
        int qb = half ? (31 - p) : p;
        int qrow0 = qb * 64 + w * 16;
        STAGE_KV(0, 0);
        const unsigned short* qg = qkv + (size_t)(qrow0 + l15) * 3072 + h * 64 + l4 * 8;
        u32x4 aq0 = *(const u32x4*)(qg);
        u32x4 aq1 = *(const u32x4*)(qg + 32);
        f32x4 o[4] = {};
        float m = BIG, ls = 0.f;
        __syncthreads();
        int cur = 0;
        for (int kt = 0; kt <= qb; ++kt) {
            if (kt < qb) STAGE_KV(cur ^ 1, kt + 1);
            f32x4 sc[4];
            __builtin_amdgcn_s_setprio(1);
#pragma unroll
            for (int n = 0; n < 4; ++n) {
                const unsigned short* kb_ = &Ks[cur][(n * 16 + l15) * 64];
                u32x4 b0 = *(const u32x4*)(kb_ + sw0);
                u32x4 b1 = *(const u32x4*)(kb_ + sw1);
                f32x4 z = {};
                z = mfma_bf16(b0, aq0, z);
                z = mfma_bf16(b1, aq1, z);
                sc[n] = z;
            }
            __builtin_amdgcn_s_setprio(0);
            if (kt == qb) {
                int qloc = w * 16 + l15;
#pragma unroll
                for (int n = 0; n < 4; ++n)
#pragma unroll
                    for (int r = 0; r < 4; ++r)
                        if (n * 16 + l4 * 4 + r > qloc) sc[n][r] = BIG;
            }
            float rmax = BIG;
#pragma unroll
            for (int n = 0; n < 4; ++n)
#pragma unroll
                for (int r = 0; r < 4; ++r) rmax = fmaxf(rmax, sc[n][r]);
            rmax = fmaxf(rmax, __shfl_xor(rmax, 16));
            rmax = fmaxf(rmax, __shfl_xor(rmax, 32));
            if (__ballot(rmax - m > THR)) {
                float mn = fmaxf(m, rmax);
                float al = __builtin_exp2f((m - mn) * SC2);
                m = mn;
                ls *= al;
#pragma unroll
                for (int nd = 0; nd < 4; ++nd)
#pragma unroll
                    for (int r = 0; r < 4; ++r) o[nd][r] *= al;
            }
            float ms = m * SC2, rs = 0.f;
#pragma unroll
            for (int n = 0; n < 4; ++n)
#pragma unroll
                for (int r = 0; r < 4; ++r) {
                    float pe = __builtin_exp2f(__builtin_fmaf(sc[n][r], SC2, -ms));
                    sc[n][r] = pe;
                    rs += pe;
                }
            rs += __shfl_xor(rs, 16);
            rs += __shfl_xor(rs, 32);
            ls += rs;
            unsigned pk0[2], pk1[2], pk2[2], pk3[2];
#pragma unroll
            for (int rr = 0; rr < 2; ++rr) {
                pk0[rr] = cvt_pk_bf16(sc[0][2*rr], sc[0][2*rr+1]);
                pk1[rr] = cvt_pk_bf16(sc[1][2*rr], sc[1][2*rr+1]);
                pk2[rr] = cvt_pk_bf16(sc[2][2*rr], sc[2][2*rr+1]);
                pk3[rr] = cvt_pk_bf16(sc[3][2*rr], sc[3][2*rr+1]);
            }
            u32x4 W1, W2;
            {
                unsigned a0, a1;
                a0 = __shfl(pk0[0], srcA); a1 = __shfl(pk1[0], srcA); W1[0] = hi32 ? a1 : a0;
                a0 = __shfl(pk0[1], srcA); a1 = __shfl(pk1[1], srcA); W1[1] = hi32 ? a1 : a0;
                a0 = __shfl(pk0[0], srcB); a1 = __shfl(pk1[0], srcB); W1[2] = hi32 ? a1 : a0;
                a0 = __shfl(pk0[1], srcB); a1 = __shfl(pk1[1], srcB); W1[3] = hi32 ? a1 : a0;
                a0 = __shfl(pk2[0], srcA); a1 = __shfl(pk3[0], srcA); W2[0] = hi32 ? a1 : a0;
                a0 = __shfl(pk2[1], srcA); a1 = __shfl(pk3[1], srcA); W2[1] = hi32 ? a1 : a0;
                a0 = __shfl(pk2[0], srcB); a1 = __shfl(pk3[0], srcB); W2[2] = hi32 ? a1 : a0;
                a0 = __shfl(pk2[1], srcB); a1 = __shfl(pk3[1], srcB); W2[3] = hi32 ? a1 : a0;
            }
            __builtin_amdgcn_s_setprio(1);
#pragma unroll
            for (int nd = 0; nd < 4; ++nd) {
                const unsigned short* vb = &Vs[cur][(nd * 16 + l15) * 64];
                u32x4 bv0 = *(const u32x4*)(vb + sw0);
                u32x4 bv1 = *(const u32x4*)(vb + sw1);
                o[nd] = mfma_bf16(bv0, W1, o[nd]);
                o[nd] = mfma_bf16(bv1, W2, o[nd]);
            }
            __builtin_amdgcn_s_setprio(0);
            __syncthreads();
            cur ^= 1;
        }
#undef STAGE_KV
        float linv = 1.0f / ls;
        unsigned short* orow = out + (size_t)(qrow0 + l15) * HID + h * 64 + l4 * 4;
#pragma unroll
        for (int nd = 0; nd < 4; ++nd) {
            u32x2 wv;
            wv[0] = cvt_pk_bf16(o[nd][0] * linv, o[nd][1] * linv);
            wv[1] = cvt_pk_bf16(o[nd][2] * linv, o[nd][3] * linv);
            *(u32x2*)(orow + nd * 16) = wv;
        }
    }
}

extern "C" void kernel_launch(void* const* d_in, const int* in_sizes, int n_in,
                              void* d_out, int out_size, void* d_ws, size_t ws_size,
                              hipStream_t stream)
{
    const float* x     = (const float*)d_in[0];
    const float* sin_t = (const float*)d_in[1];
    const float* cos_t = (const float*)d_in[2];
    const float* ln1w  = (const float*)d_in[3];
    const float* ln2w  = (const float*)d_in[4];
    const float* wq    = (const float*)d_in[5];
    const float* wk    = (const float*)d_in[6];
    const float* wv    = (const float*)d_in[7];
    const float* wo    = (const float*)d_in[8];
    const float* wg    = (const float*)d_in[9];
    const float* wu    = (const float*)d_in[10];
    const float* wd    = (const float*)d_in[11];
    float* out = (float*)d_out;

    char* ws = (char*)d_ws;
    if (ws_size < 113246208u) return;
    unsigned short* wT    = (unsigned short*)(ws);                 // [0, 33.5MB)
    unsigned short* xn    = (unsigned short*)(ws + 33554432u);     // [33.5, 41.9MB)
    unsigned short* qkv   = (unsigned short*)(ws + 41943040u);     // [41.9, 54.5MB) attn window
    unsigned short* attn  = (unsigned short*)(ws + 54525952u);     // [54.5, 62.9MB)
    unsigned short* vT    = (unsigned short*)(ws + 62914560u);     // [62.9, 65.0MB)
    unsigned short* wuT   = (unsigned short*)(ws + 41943040u);     // [41.9, 75.4MB) MLP window
    _Float16*       part  = (_Float16*)(ws + 41943040u);           // [41.9, 75.4MB) down window
    unsigned short* g     = (unsigned short*)(ws + 79691776u);     // [79.7, 113.2MB)
    _Float16*       opart = (_Float16*)(ws + 79691776u);           // o-proj window
    _Float16*       qpart = (_Float16*)(ws + 79691776u);           // qkv-proj window

    hipFuncSetAttribute(reinterpret_cast<const void*>(&gemm8p<5>),
                        hipFuncAttributeMaxDynamicSharedMemorySize, 131072);
    hipFuncSetAttribute(reinterpret_cast<const void*>(&gemm8p_gu),
                        hipFuncAttributeMaxDynamicSharedMemorySize, 131072);

    // x -> rmsnorm -> xn (bf16)
    rmsnorm_k<<<S_LEN, 256, 0, stream>>>(x, ln1w, xn);

    // wq|wk|wv -> wT as [3072][2048] transposed bf16
    transpose_cvt<<<dim3(32, 32), 256, 0, stream>>>(wq, wT, 2048, 2048);
    transpose_cvt<<<dim3(8, 32), 256, 0, stream>>>(wk, wT + (size_t)2048 * 2048, 2048, 512);
    transpose_cvt<<<dim3(8, 32), 256, 0, stream>>>(wv, wT + (size_t)2560 * 2048, 2048, 512);

    // qkv partials = xn @ [wq wk wv]   [split-K=2, f16 partials]
    gemm8p<5><<<dim3(96, 2), 512, 131072, stream>>>(xn, wT, qpart, nullptr, 2048, 3072, 1024, 2048);

    // fused: qkv = reduce(partials) + rope(q,k) + bf16 convert  [vectorized]
    reduce_rope<<<S_LEN, 256, 0, stream>>>(qpart, sin_t, cos_t, qkv, 6291456);

    // v -> vT (swizzled)
    transpose_v<<<dim3(32, 8), 256, 0, stream>>>(qkv, vT);

    // attention (paired q-tiles: blocks do exactly 33 kv-tiles each)
    attn_fwd<<<dim3(16, 32), 256, 0, stream>>>(qkv, vT, attn);

    // o-proj: split-K=4 (f16 partials)
    transpose_cvt<<<dim3(32, 32), 256, 0, stream>>>(wo, wT, 2048, 2048);
    gemm8p<5><<<dim3(64, 4), 512, 131072, stream>>>(attn, wT, opart, nullptr, 2048, 2048, 512, 2048);

    // fused: d_out = x1 = x + Σp ; xn = rmsnorm(x1, ln2w)
    res_rms<<<S_LEN, 256, 0, stream>>>(x, opart, ln2w, out, xn, 4194304);

    // fused gate+up: g = silu(xn @ w_gate) * (xn @ w_up)
    transpose_cvt<<<dim3(128, 32), 256, 0, stream>>>(wg, wT, 2048, 8192);
    transpose_cvt<<<dim3(128, 32), 256, 0, stream>>>(wu, wuT, 2048, 8192);
    gemm8p_gu<<<dim3(512), 512, 131072, stream>>>(xn, wT, wuT, g, 2048, 8192, 2048);

    // down split-K=4 (f16 partials)
    transpose_cvt<<<dim3(32, 128), 256, 0, stream>>>(wd, wT, 8192, 2048);
    gemm8p<5><<<dim3(64, 4), 512, 131072, stream>>>(g, wT, part, nullptr, 2048, 2048, 2048, 8192);

    // d_out (holds x1) += part0+part1+part2+part3
    reduce_add4<<<4096, 256, 0, stream>>>(out, part, 4194304);
}